// Round 1
// baseline (1154.196 us; speedup 1.0000x reference)
//
#include <hip/hip_runtime.h>
#include <math.h>

#define DIM 64
#define NEG_SLOPE 0.01f

// ---------------- degree / norm build ----------------

__global__ void k_deg_init(float* __restrict__ deg, int n) {
    int i = blockIdx.x * blockDim.x + threadIdx.x;
    if (i < n) deg[i] = 1.0f;  // self-loop contribution
}

__global__ void k_deg_count(const int* __restrict__ ei, int E, float* __restrict__ deg) {
    int e = blockIdx.x * blockDim.x + threadIdx.x;
    if (e < E) {
        // symmetrized graph: edge (u,v) contributes deg[v] += 1 and deg[u] += 1
        atomicAdd(deg + ei[e], 1.0f);
        atomicAdd(deg + ei[E + e], 1.0f);
    }
}

__global__ void k_dinv(float* __restrict__ deg, int n) {
    int i = blockIdx.x * blockDim.x + threadIdx.x;
    if (i < n) deg[i] = rsqrtf(deg[i]);  // deg >= 1 always (self loops)
}

// ---------------- row L2-normalize (F.normalize) ----------------

__global__ void k_normalize(const float* __restrict__ x, float* __restrict__ xn, int n) {
    int row  = (blockIdx.x * blockDim.x + threadIdx.x) >> 6;  // wave per row
    int lane = threadIdx.x & 63;
    if (row >= n) return;
    float v = x[row * DIM + lane];
    float s = v * v;
    #pragma unroll
    for (int off = 32; off; off >>= 1) s += __shfl_xor(s, off);
    float scale = 1.0f / fmaxf(sqrtf(s), 1e-12f);
    xn[row * DIM + lane] = v * scale;
}

// ---------------- propagation: agg = A_norm @ src ----------------

__global__ void k_prop_init(const float* __restrict__ src, const float* __restrict__ dinv,
                            float* __restrict__ agg, int n) {
    int i = blockIdx.x * blockDim.x + threadIdx.x;  // over n*DIM
    if (i < n * DIM) {
        float d = dinv[i >> 6];
        agg[i] = src[i] * d * d;  // self-loop term, also fully initializes agg
    }
}

__global__ void k_prop_edges(const int* __restrict__ ei, int E,
                             const float* __restrict__ dinv,
                             const float* __restrict__ src,
                             float* __restrict__ agg) {
    int w    = (blockIdx.x * blockDim.x + threadIdx.x) >> 6;  // wave per original edge
    int lane = threadIdx.x & 63;
    if (w >= E) return;
    int u = ei[w];
    int v = ei[E + w];
    float nrm = dinv[u] * dinv[v];  // symmetric: same norm both directions
    float su = src[u * DIM + lane] * nrm;
    float sv = src[v * DIM + lane] * nrm;
    atomicAdd(agg + v * DIM + lane, su);  // direction u->v
    atomicAdd(agg + u * DIM + lane, sv);  // direction v->u
}

// ---------------- x1 = lrelu(agg @ W1^T + b1) ----------------
// block = 256 threads = 4 waves; 16 rows per block; lane = output dim.
// Each lane preloads its row of W (W[lane][k], k=0..63) into 16 float4 regs.

__global__ void k_linear(const float* __restrict__ in, const float* __restrict__ W,
                         const float* __restrict__ b, float* __restrict__ out,
                         int n, int apply_lrelu) {
    __shared__ float sIn[16 * DIM];
    int tid = threadIdx.x;
    int r0  = blockIdx.x * 16;
    int lim = (n - r0 < 16 ? n - r0 : 16) * DIM;
    for (int idx = tid; idx < lim; idx += 256) sIn[idx] = in[(size_t)r0 * DIM + idx];
    __syncthreads();
    int lane = tid & 63;
    int wv   = tid >> 6;
    float4 wreg[16];
    const float4* W4 = (const float4*)(W + lane * DIM);
    #pragma unroll
    for (int i = 0; i < 16; i++) wreg[i] = W4[i];
    float bias = b[lane];
    #pragma unroll
    for (int rr = 0; rr < 4; rr++) {
        int r = r0 + wv * 4 + rr;
        if (r >= n) break;
        const float* row = &sIn[(wv * 4 + rr) * DIM];
        float acc = bias;
        #pragma unroll
        for (int i = 0; i < 16; i++) {
            acc = fmaf(row[4*i+0], wreg[i].x, acc);
            acc = fmaf(row[4*i+1], wreg[i].y, acc);
            acc = fmaf(row[4*i+2], wreg[i].z, acc);
            acc = fmaf(row[4*i+3], wreg[i].w, acc);
        }
        if (apply_lrelu) acc = acc > 0.f ? acc : NEG_SLOPE * acc;
        out[(size_t)r * DIM + lane] = acc;
    }
}

// ---------------- final: out = xn + x1 + lrelu(agg@W2^T+b2) + (agg@W3^T+b3) ----------------

__global__ void k_final(const float* __restrict__ agg, const float* __restrict__ xn,
                        const float* __restrict__ x1,
                        const float* __restrict__ W2, const float* __restrict__ b2,
                        const float* __restrict__ W3, const float* __restrict__ b3,
                        float* __restrict__ out, int n) {
    __shared__ float sIn[16 * DIM];
    int tid = threadIdx.x;
    int r0  = blockIdx.x * 16;
    int lim = (n - r0 < 16 ? n - r0 : 16) * DIM;
    for (int idx = tid; idx < lim; idx += 256) sIn[idx] = agg[(size_t)r0 * DIM + idx];
    __syncthreads();
    int lane = tid & 63;
    int wv   = tid >> 6;
    float4 w2reg[16], w3reg[16];
    const float4* W24 = (const float4*)(W2 + lane * DIM);
    const float4* W34 = (const float4*)(W3 + lane * DIM);
    #pragma unroll
    for (int i = 0; i < 16; i++) { w2reg[i] = W24[i]; w3reg[i] = W34[i]; }
    float bias2 = b2[lane], bias3 = b3[lane];
    #pragma unroll
    for (int rr = 0; rr < 4; rr++) {
        int r = r0 + wv * 4 + rr;
        if (r >= n) break;
        const float* row = &sIn[(wv * 4 + rr) * DIM];
        float a2 = bias2, a3 = bias3;
        #pragma unroll
        for (int i = 0; i < 16; i++) {
            a2 = fmaf(row[4*i+0], w2reg[i].x, a2);
            a2 = fmaf(row[4*i+1], w2reg[i].y, a2);
            a2 = fmaf(row[4*i+2], w2reg[i].z, a2);
            a2 = fmaf(row[4*i+3], w2reg[i].w, a2);
            a3 = fmaf(row[4*i+0], w3reg[i].x, a3);
            a3 = fmaf(row[4*i+1], w3reg[i].y, a3);
            a3 = fmaf(row[4*i+2], w3reg[i].z, a3);
            a3 = fmaf(row[4*i+3], w3reg[i].w, a3);
        }
        float x2v = a2 > 0.f ? a2 : NEG_SLOPE * a2;
        size_t idx = (size_t)r * DIM + lane;
        out[idx] = xn[idx] + x1[idx] + x2v + a3;
    }
}

// ---------------- launcher ----------------

extern "C" void kernel_launch(void* const* d_in, const int* in_sizes, int n_in,
                              void* d_out, int out_size, void* d_ws, size_t ws_size,
                              hipStream_t stream) {
    const int*   ei  = (const int*)d_in[0];     // edge_index [2][E] (int32 per harness)
    const float* emb = (const float*)d_in[1];   // [n][64]
    const float* W1  = (const float*)d_in[2];
    const float* b1  = (const float*)d_in[3];
    const float* W2  = (const float*)d_in[4];
    const float* b2  = (const float*)d_in[5];
    const float* W3  = (const float*)d_in[6];
    const float* b3  = (const float*)d_in[7];
    float* out = (float*)d_out;

    int E = in_sizes[0] / 2;
    int n = in_sizes[1] / DIM;

    // workspace layout (all fully initialized each call)
    float* dinv = (float*)d_ws;                       // n floats (deg -> dinv in place)
    float* xn   = dinv + (((size_t)n + 63) & ~63ull); // n*DIM
    float* x1   = xn + (size_t)n * DIM;               // n*DIM
    float* agg  = x1 + (size_t)n * DIM;               // n*DIM

    const int B = 256;

    // graph norm build
    k_deg_init <<<(n + B - 1) / B, B, 0, stream>>>(dinv, n);
    k_deg_count<<<(E + B - 1) / B, B, 0, stream>>>(ei, E, dinv);
    k_dinv     <<<(n + B - 1) / B, B, 0, stream>>>(dinv, n);

    // xn = row-L2-normalized embedding
    k_normalize<<<(n + 3) / 4, B, 0, stream>>>(emb, xn, n);

    // agg = A_norm @ xn
    k_prop_init <<<((size_t)n * DIM + B - 1) / B, B, 0, stream>>>(xn, dinv, agg, n);
    k_prop_edges<<<(E + 3) / 4, B, 0, stream>>>(ei, E, dinv, xn, agg);

    // x1 = lrelu(agg @ W1^T + b1)
    k_linear<<<(n + 15) / 16, B, 0, stream>>>(agg, W1, b1, x1, n, 1);

    // agg = A_norm @ x1
    k_prop_init <<<((size_t)n * DIM + B - 1) / B, B, 0, stream>>>(x1, dinv, agg, n);
    k_prop_edges<<<(E + 3) / 4, B, 0, stream>>>(ei, E, dinv, x1, agg);

    // out = xn + x1 + lrelu(agg@W2^T+b2) + (agg@W3^T+b3)
    k_final<<<(n + 15) / 16, B, 0, stream>>>(agg, xn, x1, W2, b2, W3, b3, out, n);
}

// Round 2
// 558.134 us; speedup vs baseline: 2.0680x; 2.0680x over previous
//
#include <hip/hip_runtime.h>
#include <math.h>

#define DIM 64
#define NEG_SLOPE 0.01f

// ---------------- small utility ----------------

__global__ void k_zero_i32(int* __restrict__ p, int n) {
    int i = blockIdx.x * blockDim.x + threadIdx.x;
    if (i < n) p[i] = 0;
}

// count in-degree over symmetrized edges (int atomics on 400KB array: L2-resident)
__global__ void k_deg_count(const int* __restrict__ ei, int E, int* __restrict__ degi) {
    int e = blockIdx.x * blockDim.x + threadIdx.x;
    if (e < E) {
        atomicAdd(degi + ei[e], 1);
        atomicAdd(degi + ei[E + e], 1);
    }
}

// dinv = rsqrt(1 + deg)  (self loop included)
__global__ void k_dinv(const int* __restrict__ degi, float* __restrict__ dinv, int n) {
    int i = blockIdx.x * blockDim.x + threadIdx.x;
    if (i < n) dinv[i] = rsqrtf(1.0f + (float)degi[i]);
}

// ---------------- exclusive scan of degi -> offsets (n up to ~250K) ----------------
// A: per-block (1024 elems) sums
__global__ void k_scanA(const int* __restrict__ degi, int n, int* __restrict__ bsums) {
    __shared__ int ls[256];
    int t = threadIdx.x;
    int base = blockIdx.x * 1024 + t * 4;
    int s = 0;
    #pragma unroll
    for (int k = 0; k < 4; k++) { int i = base + k; if (i < n) s += degi[i]; }
    ls[t] = s; __syncthreads();
    for (int off = 128; off; off >>= 1) {
        if (t < off) ls[t] += ls[t + off];
        __syncthreads();
    }
    if (t == 0) bsums[blockIdx.x] = ls[0];
}

// B: exclusive scan of block sums (nb <= 1024), also writes offsets[n] = total
__global__ void k_scanB(int* __restrict__ bsums, int nb, int* __restrict__ offsets, int n) {
    __shared__ int ls[1024];
    int t = threadIdx.x;
    for (int i = t; i < nb; i += 256) ls[i] = bsums[i];
    __syncthreads();
    if (t == 0) {
        int run = 0;
        for (int i = 0; i < nb; i++) { int v = ls[i]; ls[i] = run; run += v; }
        offsets[n] = run;
    }
    __syncthreads();
    for (int i = t; i < nb; i += 256) bsums[i] = ls[i];
}

// C: per-block exclusive scan + block base -> offsets; also zero cursor
__global__ void k_scanC(const int* __restrict__ degi, int n, const int* __restrict__ bsums,
                        int* __restrict__ offsets, int* __restrict__ cursor) {
    __shared__ int ls[256];
    int t = threadIdx.x;
    int base = blockIdx.x * 1024 + t * 4;
    int a[4]; int s = 0;
    #pragma unroll
    for (int k = 0; k < 4; k++) { int i = base + k; a[k] = (i < n) ? degi[i] : 0; s += a[k]; }
    ls[t] = s; __syncthreads();
    // Hillis-Steele inclusive scan over thread sums
    for (int off = 1; off < 256; off <<= 1) {
        int v = (t >= off) ? ls[t - off] : 0;
        __syncthreads();
        ls[t] += v;
        __syncthreads();
    }
    int run = bsums[blockIdx.x] + ls[t] - s;  // exclusive base for this thread
    #pragma unroll
    for (int k = 0; k < 4; k++) {
        int i = base + k;
        if (i < n) { offsets[i] = run; cursor[i] = 0; }
        run += a[k];
    }
}

// ---------------- scatter edges into CSR (adj index + premultiplied norm) ----------------
__global__ void k_scatter(const int* __restrict__ ei, int E, const float* __restrict__ dinv,
                          const int* __restrict__ offsets, int* __restrict__ cursor,
                          int2* __restrict__ adjw) {
    int e = blockIdx.x * blockDim.x + threadIdx.x;
    if (e >= E) return;
    int u = ei[e];
    int v = ei[E + e];
    float w = dinv[u] * dinv[v];
    int wb = __float_as_int(w);
    int s1 = offsets[v] + atomicAdd(cursor + v, 1);
    adjw[s1] = make_int2(u, wb);
    int s2 = offsets[u] + atomicAdd(cursor + u, 1);
    adjw[s2] = make_int2(v, wb);
}

// ---------------- row L2-normalize (F.normalize) ----------------
__global__ void k_normalize(const float* __restrict__ x, float* __restrict__ xn, int n) {
    int row  = (blockIdx.x * blockDim.x + threadIdx.x) >> 6;
    int lane = threadIdx.x & 63;
    if (row >= n) return;
    float v = x[row * DIM + lane];
    float s = v * v;
    #pragma unroll
    for (int off = 32; off; off >>= 1) s += __shfl_xor(s, off);
    float scale = 1.0f / fmaxf(sqrtf(s), 1e-12f);
    xn[row * DIM + lane] = v * scale;
}

// ---------------- CSR gather: dst[d] = dinv[d]^2*src[d] + sum_j w_j * src[adj_j] ----------------
__global__ void k_gather(const int2* __restrict__ adjw, const int* __restrict__ offsets,
                         const float* __restrict__ dinv, const float* __restrict__ src,
                         float* __restrict__ dst, int n) {
    int w    = (blockIdx.x * blockDim.x + threadIdx.x) >> 6;  // wave per node
    int lane = threadIdx.x & 63;
    if (w >= n) return;
    int beg = offsets[w], end = offsets[w + 1];
    float dd = dinv[w];
    float acc = src[(size_t)w * DIM + lane] * dd * dd;  // self loop
    int j = beg;
    for (; j + 4 <= end; j += 4) {
        int2 e0 = adjw[j], e1 = adjw[j + 1], e2 = adjw[j + 2], e3 = adjw[j + 3];
        float v0 = src[(size_t)e0.x * DIM + lane];
        float v1 = src[(size_t)e1.x * DIM + lane];
        float v2 = src[(size_t)e2.x * DIM + lane];
        float v3 = src[(size_t)e3.x * DIM + lane];
        acc = fmaf(__int_as_float(e0.y), v0, acc);
        acc = fmaf(__int_as_float(e1.y), v1, acc);
        acc = fmaf(__int_as_float(e2.y), v2, acc);
        acc = fmaf(__int_as_float(e3.y), v3, acc);
    }
    for (; j < end; ++j) {
        int2 e = adjw[j];
        acc = fmaf(__int_as_float(e.y), src[(size_t)e.x * DIM + lane], acc);
    }
    dst[(size_t)w * DIM + lane] = acc;
}

// ---------------- x1 = lrelu(agg @ W1^T + b1) ----------------
__global__ void k_linear(const float* __restrict__ in, const float* __restrict__ W,
                         const float* __restrict__ b, float* __restrict__ out,
                         int n, int apply_lrelu) {
    __shared__ float sIn[16 * DIM];
    int tid = threadIdx.x;
    int r0  = blockIdx.x * 16;
    int lim = (n - r0 < 16 ? n - r0 : 16) * DIM;
    for (int idx = tid; idx < lim; idx += 256) sIn[idx] = in[(size_t)r0 * DIM + idx];
    __syncthreads();
    int lane = tid & 63;
    int wv   = tid >> 6;
    float4 wreg[16];
    const float4* W4 = (const float4*)(W + lane * DIM);
    #pragma unroll
    for (int i = 0; i < 16; i++) wreg[i] = W4[i];
    float bias = b[lane];
    #pragma unroll
    for (int rr = 0; rr < 4; rr++) {
        int r = r0 + wv * 4 + rr;
        if (r >= n) break;
        const float* row = &sIn[(wv * 4 + rr) * DIM];
        float acc = bias;
        #pragma unroll
        for (int i = 0; i < 16; i++) {
            acc = fmaf(row[4*i+0], wreg[i].x, acc);
            acc = fmaf(row[4*i+1], wreg[i].y, acc);
            acc = fmaf(row[4*i+2], wreg[i].z, acc);
            acc = fmaf(row[4*i+3], wreg[i].w, acc);
        }
        if (apply_lrelu) acc = acc > 0.f ? acc : NEG_SLOPE * acc;
        out[(size_t)r * DIM + lane] = acc;
    }
}

// ---------------- final: out = xn + x1 + lrelu(agg@W2^T+b2) + (agg@W3^T+b3) ----------------
__global__ void k_final(const float* __restrict__ agg, const float* __restrict__ xn,
                        const float* __restrict__ x1,
                        const float* __restrict__ W2, const float* __restrict__ b2,
                        const float* __restrict__ W3, const float* __restrict__ b3,
                        float* __restrict__ out, int n) {
    __shared__ float sIn[16 * DIM];
    int tid = threadIdx.x;
    int r0  = blockIdx.x * 16;
    int lim = (n - r0 < 16 ? n - r0 : 16) * DIM;
    for (int idx = tid; idx < lim; idx += 256) sIn[idx] = agg[(size_t)r0 * DIM + idx];
    __syncthreads();
    int lane = tid & 63;
    int wv   = tid >> 6;
    float4 w2reg[16], w3reg[16];
    const float4* W24 = (const float4*)(W2 + lane * DIM);
    const float4* W34 = (const float4*)(W3 + lane * DIM);
    #pragma unroll
    for (int i = 0; i < 16; i++) { w2reg[i] = W24[i]; w3reg[i] = W34[i]; }
    float bias2 = b2[lane], bias3 = b3[lane];
    #pragma unroll
    for (int rr = 0; rr < 4; rr++) {
        int r = r0 + wv * 4 + rr;
        if (r >= n) break;
        const float* row = &sIn[(wv * 4 + rr) * DIM];
        float a2 = bias2, a3 = bias3;
        #pragma unroll
        for (int i = 0; i < 16; i++) {
            a2 = fmaf(row[4*i+0], w2reg[i].x, a2);
            a2 = fmaf(row[4*i+1], w2reg[i].y, a2);
            a2 = fmaf(row[4*i+2], w2reg[i].z, a2);
            a2 = fmaf(row[4*i+3], w2reg[i].w, a2);
            a3 = fmaf(row[4*i+0], w3reg[i].x, a3);
            a3 = fmaf(row[4*i+1], w3reg[i].y, a3);
            a3 = fmaf(row[4*i+2], w3reg[i].z, a3);
            a3 = fmaf(row[4*i+3], w3reg[i].w, a3);
        }
        float x2v = a2 > 0.f ? a2 : NEG_SLOPE * a2;
        size_t idx = (size_t)r * DIM + lane;
        out[idx] = xn[idx] + x1[idx] + x2v + a3;
    }
}

// ---------------- launcher ----------------

extern "C" void kernel_launch(void* const* d_in, const int* in_sizes, int n_in,
                              void* d_out, int out_size, void* d_ws, size_t ws_size,
                              hipStream_t stream) {
    const int*   ei  = (const int*)d_in[0];
    const float* emb = (const float*)d_in[1];
    const float* W1  = (const float*)d_in[2];
    const float* b1  = (const float*)d_in[3];
    const float* W2  = (const float*)d_in[4];
    const float* b2  = (const float*)d_in[5];
    const float* W3  = (const float*)d_in[6];
    const float* b3  = (const float*)d_in[7];
    float* out = (float*)d_out;

    int E = in_sizes[0] / 2;
    int n = in_sizes[1] / DIM;
    int nE2 = 2 * E;  // directed edges

    // workspace layout (all fully initialized each call)
    size_t np = ((size_t)n + 255) & ~255ull;
    int*   degi    = (int*)d_ws;            // n
    int*   offsets = degi + np;             // n+1
    int*   cursor  = offsets + np + 256;    // n
    int*   bsums   = cursor + np;           // ~nb (<=1024)
    float* dinv    = (float*)(bsums + 1024);// n
    float* xn      = dinv + np;             // n*DIM
    float* x1      = xn + (size_t)n * DIM;  // n*DIM
    float* agg     = x1 + (size_t)n * DIM;  // n*DIM
    int2*  adjw    = (int2*)(agg + (size_t)n * DIM);  // 2E entries (16MB)

    const int B = 256;
    int nb = (n + 1023) / 1024;  // scan blocks

    // --- CSR build ---
    k_zero_i32 <<<(n + B - 1) / B, B, 0, stream>>>(degi, n);
    k_deg_count<<<(E + B - 1) / B, B, 0, stream>>>(ei, E, degi);
    k_dinv     <<<(n + B - 1) / B, B, 0, stream>>>(degi, dinv, n);
    k_scanA    <<<nb, B, 0, stream>>>(degi, n, bsums);
    k_scanB    <<<1, B, 0, stream>>>(bsums, nb, offsets, n);
    k_scanC    <<<nb, B, 0, stream>>>(degi, n, bsums, offsets, cursor);
    k_scatter  <<<(E + B - 1) / B, B, 0, stream>>>(ei, E, dinv, offsets, cursor, adjw);

    // --- xn = row-L2-normalized embedding ---
    k_normalize<<<(n + 3) / 4, B, 0, stream>>>(emb, xn, n);

    // --- agg = A_norm @ xn ; x1 = lrelu(agg @ W1^T + b1) ---
    k_gather<<<(n + 3) / 4, B, 0, stream>>>(adjw, offsets, dinv, xn, agg, n);
    k_linear<<<(n + 15) / 16, B, 0, stream>>>(agg, W1, b1, x1, n, 1);

    // --- agg = A_norm @ x1 ; out = xn + x1 + lrelu(agg@W2^T+b2) + (agg@W3^T+b3) ---
    k_gather<<<(n + 3) / 4, B, 0, stream>>>(adjw, offsets, dinv, x1, agg, n);
    k_final<<<(n + 15) / 16, B, 0, stream>>>(agg, xn, x1, W2, b2, W3, b3, out, n);
}

// Round 3
// 431.532 us; speedup vs baseline: 2.6746x; 1.2934x over previous
//
#include <hip/hip_runtime.h>
#include <math.h>

#define DIM 64
#define NEG_SLOPE 0.01f

// ---------------- small utility ----------------

__global__ void k_zero_i32(int* __restrict__ p, int n) {
    int i = blockIdx.x * blockDim.x + threadIdx.x;
    if (i < n) p[i] = 0;
}

// count in-degree over symmetrized edges (int atomics on 400KB array: L2-resident)
__global__ void k_deg_count(const int* __restrict__ ei, int E, int* __restrict__ degi) {
    int e = blockIdx.x * blockDim.x + threadIdx.x;
    if (e < E) {
        atomicAdd(degi + ei[e], 1);
        atomicAdd(degi + ei[E + e], 1);
    }
}

// dinv = rsqrt(1 + deg)  (self loop included)
__global__ void k_dinv(const int* __restrict__ degi, float* __restrict__ dinv, int n) {
    int i = blockIdx.x * blockDim.x + threadIdx.x;
    if (i < n) dinv[i] = rsqrtf(1.0f + (float)degi[i]);
}

// ---------------- exclusive scan of degi -> offsets ----------------
__global__ void k_scanA(const int* __restrict__ degi, int n, int* __restrict__ bsums) {
    __shared__ int ls[256];
    int t = threadIdx.x;
    int base = blockIdx.x * 1024 + t * 4;
    int s = 0;
    #pragma unroll
    for (int k = 0; k < 4; k++) { int i = base + k; if (i < n) s += degi[i]; }
    ls[t] = s; __syncthreads();
    for (int off = 128; off; off >>= 1) {
        if (t < off) ls[t] += ls[t + off];
        __syncthreads();
    }
    if (t == 0) bsums[blockIdx.x] = ls[0];
}

__global__ void k_scanB(int* __restrict__ bsums, int nb, int* __restrict__ offsets, int n) {
    __shared__ int ls[1024];
    int t = threadIdx.x;
    for (int i = t; i < nb; i += 256) ls[i] = bsums[i];
    __syncthreads();
    if (t == 0) {
        int run = 0;
        for (int i = 0; i < nb; i++) { int v = ls[i]; ls[i] = run; run += v; }
        offsets[n] = run;
    }
    __syncthreads();
    for (int i = t; i < nb; i += 256) bsums[i] = ls[i];
}

__global__ void k_scanC(const int* __restrict__ degi, int n, const int* __restrict__ bsums,
                        int* __restrict__ offsets, int* __restrict__ cursor) {
    __shared__ int ls[256];
    int t = threadIdx.x;
    int base = blockIdx.x * 1024 + t * 4;
    int a[4]; int s = 0;
    #pragma unroll
    for (int k = 0; k < 4; k++) { int i = base + k; a[k] = (i < n) ? degi[i] : 0; s += a[k]; }
    ls[t] = s; __syncthreads();
    for (int off = 1; off < 256; off <<= 1) {
        int v = (t >= off) ? ls[t - off] : 0;
        __syncthreads();
        ls[t] += v;
        __syncthreads();
    }
    int run = bsums[blockIdx.x] + ls[t] - s;
    #pragma unroll
    for (int k = 0; k < 4; k++) {
        int i = base + k;
        if (i < n) { offsets[i] = run; cursor[i] = 0; }
        run += a[k];
    }
}

// ---------------- scatter edges into CSR (adj index + premultiplied norm) ----------------
__global__ void k_scatter(const int* __restrict__ ei, int E, const float* __restrict__ dinv,
                          const int* __restrict__ offsets, int* __restrict__ cursor,
                          int2* __restrict__ adjw) {
    int e = blockIdx.x * blockDim.x + threadIdx.x;
    if (e >= E) return;
    int u = ei[e];
    int v = ei[E + e];
    float w = dinv[u] * dinv[v];
    int wb = __float_as_int(w);
    int s1 = offsets[v] + atomicAdd(cursor + v, 1);
    adjw[s1] = make_int2(u, wb);
    int s2 = offsets[u] + atomicAdd(cursor + u, 1);
    adjw[s2] = make_int2(v, wb);
}

// ---------------- row L2-normalize (F.normalize) ----------------
__global__ void k_normalize(const float* __restrict__ x, float* __restrict__ xn, int n) {
    int row  = (blockIdx.x * blockDim.x + threadIdx.x) >> 6;
    int lane = threadIdx.x & 63;
    if (row >= n) return;
    float v = x[row * DIM + lane];
    float s = v * v;
    #pragma unroll
    for (int off = 32; off; off >>= 1) s += __shfl_xor(s, off);
    float scale = 1.0f / fmaxf(sqrtf(s), 1e-12f);
    xn[row * DIM + lane] = v * scale;
}

// ---------------- CSR gather: dst[d] = dinv[d]^2*src[d] + sum_j w_j * src[adj_j] ----------------
__global__ void k_gather(const int2* __restrict__ adjw, const int* __restrict__ offsets,
                         const float* __restrict__ dinv, const float* __restrict__ src,
                         float* __restrict__ dst, int n) {
    int w    = (blockIdx.x * blockDim.x + threadIdx.x) >> 6;  // wave per node
    int lane = threadIdx.x & 63;
    if (w >= n) return;
    int beg = offsets[w], end = offsets[w + 1];
    float dd = dinv[w];
    float acc = src[(size_t)w * DIM + lane] * dd * dd;  // self loop
    int j = beg;
    for (; j + 4 <= end; j += 4) {
        int2 e0 = adjw[j], e1 = adjw[j + 1], e2 = adjw[j + 2], e3 = adjw[j + 3];
        float v0 = src[(size_t)e0.x * DIM + lane];
        float v1 = src[(size_t)e1.x * DIM + lane];
        float v2 = src[(size_t)e2.x * DIM + lane];
        float v3 = src[(size_t)e3.x * DIM + lane];
        acc = fmaf(__int_as_float(e0.y), v0, acc);
        acc = fmaf(__int_as_float(e1.y), v1, acc);
        acc = fmaf(__int_as_float(e2.y), v2, acc);
        acc = fmaf(__int_as_float(e3.y), v3, acc);
    }
    for (; j < end; ++j) {
        int2 e = adjw[j];
        acc = fmaf(__int_as_float(e.y), src[(size_t)e.x * DIM + lane], acc);
    }
    dst[(size_t)w * DIM + lane] = acc;
}

// ---------------- register-tiled linear: out = [lrelu](in @ W^T + b) ----------------
// 64 rows/block, 256 threads, each thread computes a 4x4 tile.
// sIn/sW padded to 65 -> a-reads broadcast, w-reads 2-way (free).
__global__ __launch_bounds__(256) void k_linear_rt(
    const float* __restrict__ in, const float* __restrict__ W,
    const float* __restrict__ b, float* __restrict__ out,
    int n, int apply_lrelu)
{
    __shared__ float sIn[64][65];
    __shared__ float sW[64][65];
    int tid = threadIdx.x;
    int r0  = blockIdx.x * 64;
    #pragma unroll
    for (int i = 0; i < 16; i++) {
        int idx = tid + i * 256;
        sW[idx >> 6][idx & 63] = W[idx];
    }
    int lim = (n - r0 < 64 ? n - r0 : 64) * DIM;
    for (int idx = tid; idx < lim; idx += 256)
        sIn[idx >> 6][idx & 63] = in[(size_t)r0 * DIM + idx];
    __syncthreads();

    int ri = (tid >> 4) << 2;   // 0..60
    int ci = (tid & 15) << 2;   // 0..60
    float acc[4][4];
    #pragma unroll
    for (int j = 0; j < 4; j++) {
        float bj = b[ci + j];
        #pragma unroll
        for (int i = 0; i < 4; i++) acc[i][j] = bj;
    }
    #pragma unroll 4
    for (int k = 0; k < 64; k++) {
        float a0 = sIn[ri + 0][k], a1 = sIn[ri + 1][k];
        float a2 = sIn[ri + 2][k], a3 = sIn[ri + 3][k];
        float w0 = sW[ci + 0][k], w1 = sW[ci + 1][k];
        float w2 = sW[ci + 2][k], w3 = sW[ci + 3][k];
        acc[0][0] = fmaf(a0, w0, acc[0][0]); acc[0][1] = fmaf(a0, w1, acc[0][1]);
        acc[0][2] = fmaf(a0, w2, acc[0][2]); acc[0][3] = fmaf(a0, w3, acc[0][3]);
        acc[1][0] = fmaf(a1, w0, acc[1][0]); acc[1][1] = fmaf(a1, w1, acc[1][1]);
        acc[1][2] = fmaf(a1, w2, acc[1][2]); acc[1][3] = fmaf(a1, w3, acc[1][3]);
        acc[2][0] = fmaf(a2, w0, acc[2][0]); acc[2][1] = fmaf(a2, w1, acc[2][1]);
        acc[2][2] = fmaf(a2, w2, acc[2][2]); acc[2][3] = fmaf(a2, w3, acc[2][3]);
        acc[3][0] = fmaf(a3, w0, acc[3][0]); acc[3][1] = fmaf(a3, w1, acc[3][1]);
        acc[3][2] = fmaf(a3, w2, acc[3][2]); acc[3][3] = fmaf(a3, w3, acc[3][3]);
    }
    #pragma unroll
    for (int i = 0; i < 4; i++) {
        int r = r0 + ri + i;
        if (r >= n) break;
        float4 o;
        o.x = acc[i][0]; o.y = acc[i][1]; o.z = acc[i][2]; o.w = acc[i][3];
        if (apply_lrelu) {
            o.x = o.x > 0.f ? o.x : NEG_SLOPE * o.x;
            o.y = o.y > 0.f ? o.y : NEG_SLOPE * o.y;
            o.z = o.z > 0.f ? o.z : NEG_SLOPE * o.z;
            o.w = o.w > 0.f ? o.w : NEG_SLOPE * o.w;
        }
        *(float4*)&out[(size_t)r * DIM + ci] = o;
    }
}

// ---------------- final: out = xn + x1 + lrelu(agg@W2^T+b2) + (agg@W3^T+b3) ----------------
__global__ __launch_bounds__(256) void k_final_rt(
    const float* __restrict__ agg, const float* __restrict__ xn,
    const float* __restrict__ x1,
    const float* __restrict__ W2, const float* __restrict__ b2,
    const float* __restrict__ W3, const float* __restrict__ b3,
    float* __restrict__ out, int n)
{
    __shared__ float sIn[64][65];
    __shared__ float sW2[64][65];
    __shared__ float sW3[64][65];
    int tid = threadIdx.x;
    int r0  = blockIdx.x * 64;
    #pragma unroll
    for (int i = 0; i < 16; i++) {
        int idx = tid + i * 256;
        sW2[idx >> 6][idx & 63] = W2[idx];
        sW3[idx >> 6][idx & 63] = W3[idx];
    }
    int lim = (n - r0 < 64 ? n - r0 : 64) * DIM;
    for (int idx = tid; idx < lim; idx += 256)
        sIn[idx >> 6][idx & 63] = agg[(size_t)r0 * DIM + idx];
    __syncthreads();

    int ri = (tid >> 4) << 2;
    int ci = (tid & 15) << 2;
    float acc2[4][4], acc3[4][4];
    #pragma unroll
    for (int j = 0; j < 4; j++) {
        float bj2 = b2[ci + j], bj3 = b3[ci + j];
        #pragma unroll
        for (int i = 0; i < 4; i++) { acc2[i][j] = bj2; acc3[i][j] = bj3; }
    }
    #pragma unroll 2
    for (int k = 0; k < 64; k++) {
        float a0 = sIn[ri + 0][k], a1 = sIn[ri + 1][k];
        float a2 = sIn[ri + 2][k], a3 = sIn[ri + 3][k];
        float u0 = sW2[ci + 0][k], u1 = sW2[ci + 1][k];
        float u2 = sW2[ci + 2][k], u3 = sW2[ci + 3][k];
        float v0 = sW3[ci + 0][k], v1 = sW3[ci + 1][k];
        float v2 = sW3[ci + 2][k], v3 = sW3[ci + 3][k];
        acc2[0][0] = fmaf(a0, u0, acc2[0][0]); acc2[0][1] = fmaf(a0, u1, acc2[0][1]);
        acc2[0][2] = fmaf(a0, u2, acc2[0][2]); acc2[0][3] = fmaf(a0, u3, acc2[0][3]);
        acc2[1][0] = fmaf(a1, u0, acc2[1][0]); acc2[1][1] = fmaf(a1, u1, acc2[1][1]);
        acc2[1][2] = fmaf(a1, u2, acc2[1][2]); acc2[1][3] = fmaf(a1, u3, acc2[1][3]);
        acc2[2][0] = fmaf(a2, u0, acc2[2][0]); acc2[2][1] = fmaf(a2, u1, acc2[2][1]);
        acc2[2][2] = fmaf(a2, u2, acc2[2][2]); acc2[2][3] = fmaf(a2, u3, acc2[2][3]);
        acc2[3][0] = fmaf(a3, u0, acc2[3][0]); acc2[3][1] = fmaf(a3, u1, acc2[3][1]);
        acc2[3][2] = fmaf(a3, u2, acc2[3][2]); acc2[3][3] = fmaf(a3, u3, acc2[3][3]);
        acc3[0][0] = fmaf(a0, v0, acc3[0][0]); acc3[0][1] = fmaf(a0, v1, acc3[0][1]);
        acc3[0][2] = fmaf(a0, v2, acc3[0][2]); acc3[0][3] = fmaf(a0, v3, acc3[0][3]);
        acc3[1][0] = fmaf(a1, v0, acc3[1][0]); acc3[1][1] = fmaf(a1, v1, acc3[1][1]);
        acc3[1][2] = fmaf(a1, v2, acc3[1][2]); acc3[1][3] = fmaf(a1, v3, acc3[1][3]);
        acc3[2][0] = fmaf(a2, v0, acc3[2][0]); acc3[2][1] = fmaf(a2, v1, acc3[2][1]);
        acc3[2][2] = fmaf(a2, v2, acc3[2][2]); acc3[2][3] = fmaf(a2, v3, acc3[2][3]);
        acc3[3][0] = fmaf(a3, v0, acc3[3][0]); acc3[3][1] = fmaf(a3, v1, acc3[3][1]);
        acc3[3][2] = fmaf(a3, v2, acc3[3][2]); acc3[3][3] = fmaf(a3, v3, acc3[3][3]);
    }
    #pragma unroll
    for (int i = 0; i < 4; i++) {
        int r = r0 + ri + i;
        if (r >= n) break;
        size_t base = (size_t)r * DIM + ci;
        float4 vxn = *(const float4*)&xn[base];
        float4 vx1 = *(const float4*)&x1[base];
        float4 o;
        float e0 = acc2[i][0] > 0.f ? acc2[i][0] : NEG_SLOPE * acc2[i][0];
        float e1 = acc2[i][1] > 0.f ? acc2[i][1] : NEG_SLOPE * acc2[i][1];
        float e2 = acc2[i][2] > 0.f ? acc2[i][2] : NEG_SLOPE * acc2[i][2];
        float e3 = acc2[i][3] > 0.f ? acc2[i][3] : NEG_SLOPE * acc2[i][3];
        o.x = vxn.x + vx1.x + e0 + acc3[i][0];
        o.y = vxn.y + vx1.y + e1 + acc3[i][1];
        o.z = vxn.z + vx1.z + e2 + acc3[i][2];
        o.w = vxn.w + vx1.w + e3 + acc3[i][3];
        *(float4*)&out[base] = o;
    }
}

// ---------------- launcher ----------------

extern "C" void kernel_launch(void* const* d_in, const int* in_sizes, int n_in,
                              void* d_out, int out_size, void* d_ws, size_t ws_size,
                              hipStream_t stream) {
    const int*   ei  = (const int*)d_in[0];
    const float* emb = (const float*)d_in[1];
    const float* W1  = (const float*)d_in[2];
    const float* b1  = (const float*)d_in[3];
    const float* W2  = (const float*)d_in[4];
    const float* b2  = (const float*)d_in[5];
    const float* W3  = (const float*)d_in[6];
    const float* b3  = (const float*)d_in[7];
    float* out = (float*)d_out;

    int E = in_sizes[0] / 2;
    int n = in_sizes[1] / DIM;

    size_t np = ((size_t)n + 255) & ~255ull;
    int*   degi    = (int*)d_ws;
    int*   offsets = degi + np;
    int*   cursor  = offsets + np + 256;
    int*   bsums   = cursor + np;
    float* dinv    = (float*)(bsums + 1024);
    float* xn      = dinv + np;
    float* x1      = xn + (size_t)n * DIM;
    float* agg     = x1 + (size_t)n * DIM;
    int2*  adjw    = (int2*)(agg + (size_t)n * DIM);

    const int B = 256;
    int nb = (n + 1023) / 1024;

    // --- CSR build ---
    k_zero_i32 <<<(n + B - 1) / B, B, 0, stream>>>(degi, n);
    k_deg_count<<<(E + B - 1) / B, B, 0, stream>>>(ei, E, degi);
    k_dinv     <<<(n + B - 1) / B, B, 0, stream>>>(degi, dinv, n);
    k_scanA    <<<nb, B, 0, stream>>>(degi, n, bsums);
    k_scanB    <<<1, B, 0, stream>>>(bsums, nb, offsets, n);
    k_scanC    <<<nb, B, 0, stream>>>(degi, n, bsums, offsets, cursor);
    k_scatter  <<<(E + B - 1) / B, B, 0, stream>>>(ei, E, dinv, offsets, cursor, adjw);

    // --- xn = row-L2-normalized embedding ---
    k_normalize<<<(n + 3) / 4, B, 0, stream>>>(emb, xn, n);

    // --- layer 1 ---
    k_gather   <<<(n + 3) / 4, B, 0, stream>>>(adjw, offsets, dinv, xn, agg, n);
    k_linear_rt<<<(n + 63) / 64, B, 0, stream>>>(agg, W1, b1, x1, n, 1);

    // --- layers 2+3 fused ---
    k_gather   <<<(n + 3) / 4, B, 0, stream>>>(adjw, offsets, dinv, x1, agg, n);
    k_final_rt <<<(n + 63) / 64, B, 0, stream>>>(agg, xn, x1, W2, b2, W3, b3, out, n);
}

// Round 4
// 386.388 us; speedup vs baseline: 2.9871x; 1.1168x over previous
//
#include <hip/hip_runtime.h>
#include <math.h>

#define DIM 64
#define NEG_SLOPE 0.01f

// ---------------- small utility ----------------

__global__ void k_zero_i32(int* __restrict__ p, int n) {
    int i = blockIdx.x * blockDim.x + threadIdx.x;
    if (i < n) p[i] = 0;
}

// count degree over symmetrized edges (int atomics on 400KB array: L2-resident)
__global__ void k_deg_count(const int* __restrict__ ei, int E, int* __restrict__ degi) {
    int e = blockIdx.x * blockDim.x + threadIdx.x;
    if (e < E) {
        atomicAdd(degi + ei[e], 1);
        atomicAdd(degi + ei[E + e], 1);
    }
}

// dinv = rsqrt(1 + deg)  (self loop included)
__global__ void k_dinv(const int* __restrict__ degi, float* __restrict__ dinv, int n) {
    int i = blockIdx.x * blockDim.x + threadIdx.x;
    if (i < n) dinv[i] = rsqrtf(1.0f + (float)degi[i]);
}

// ---------------- exclusive scan of degi -> offsets ----------------
__global__ void k_scanA(const int* __restrict__ degi, int n, int* __restrict__ bsums) {
    __shared__ int ls[256];
    int t = threadIdx.x;
    int base = blockIdx.x * 1024 + t * 4;
    int s = 0;
    #pragma unroll
    for (int k = 0; k < 4; k++) { int i = base + k; if (i < n) s += degi[i]; }
    ls[t] = s; __syncthreads();
    for (int off = 128; off; off >>= 1) {
        if (t < off) ls[t] += ls[t + off];
        __syncthreads();
    }
    if (t == 0) bsums[blockIdx.x] = ls[0];
}

__global__ void k_scanB(int* __restrict__ bsums, int nb, int* __restrict__ offsets, int n) {
    __shared__ int ls[1024];
    int t = threadIdx.x;
    for (int i = t; i < nb; i += 256) ls[i] = bsums[i];
    __syncthreads();
    if (t == 0) {
        int run = 0;
        for (int i = 0; i < nb; i++) { int v = ls[i]; ls[i] = run; run += v; }
        offsets[n] = run;
    }
    __syncthreads();
    for (int i = t; i < nb; i += 256) bsums[i] = ls[i];
}

__global__ void k_scanC(const int* __restrict__ degi, int n, const int* __restrict__ bsums,
                        int* __restrict__ offsets) {
    __shared__ int ls[256];
    int t = threadIdx.x;
    int base = blockIdx.x * 1024 + t * 4;
    int a[4]; int s = 0;
    #pragma unroll
    for (int k = 0; k < 4; k++) { int i = base + k; a[k] = (i < n) ? degi[i] : 0; s += a[k]; }
    ls[t] = s; __syncthreads();
    for (int off = 1; off < 256; off <<= 1) {
        int v = (t >= off) ? ls[t - off] : 0;
        __syncthreads();
        ls[t] += v;
        __syncthreads();
    }
    int run = bsums[blockIdx.x] + ls[t] - s;
    #pragma unroll
    for (int k = 0; k < 4; k++) {
        int i = base + k;
        if (i < n) offsets[i] = run;
        run += a[k];
    }
}

// ---------------- binned CSR build ----------------
// bucket b covers nodes [b<<shift, (b+1)<<shift); its stage region is the exact
// CSR range [offsets[b<<shift], offsets[(b+1)<<shift]) -- no overflow possible.

__global__ void k_bcur_init(const int* __restrict__ offsets, int* __restrict__ bcur,
                            int shift, int nbuckets) {
    int b = blockIdx.x * blockDim.x + threadIdx.x;
    if (b < nbuckets) bcur[b] = offsets[(size_t)b << shift];
}

#define EPW 2048  // edges per workgroup in k_bin

__global__ __launch_bounds__(256) void k_bin(const int* __restrict__ ei, int E,
                                             int2* __restrict__ stage,
                                             int* __restrict__ bcur, int shift) {
    __shared__ int hist[256];
    __shared__ int cur[256];
    int t = threadIdx.x;
    hist[t] = 0;
    __syncthreads();
    int e0 = blockIdx.x * EPW;
    int e1 = e0 + EPW < E ? e0 + EPW : E;
    for (int e = e0 + t; e < e1; e += 256) {
        int u = ei[e], v = ei[E + e];
        atomicAdd(&hist[u >> shift], 1);
        atomicAdd(&hist[v >> shift], 1);
    }
    __syncthreads();
    cur[t] = hist[t] > 0 ? atomicAdd(&bcur[t], hist[t]) : 0;
    __syncthreads();
    for (int e = e0 + t; e < e1; e += 256) {
        int u = ei[e], v = ei[E + e];
        int s1 = atomicAdd(&cur[v >> shift], 1);
        stage[s1] = make_int2(v, u);
        int s2 = atomicAdd(&cur[u >> shift], 1);
        stage[s2] = make_int2(u, v);
    }
}

// one workgroup per bucket: finish the sort with LDS per-node cursors.
__global__ __launch_bounds__(256) void k_bsort(const int2* __restrict__ stage,
                                               const int* __restrict__ offsets,
                                               int* __restrict__ adjw, int n, int shift) {
    __shared__ int cur[2048];
    int t = threadIdx.x;
    int span  = 1 << shift;
    int node0 = blockIdx.x << shift;
    int nodeN = node0 + span < n ? node0 + span : n;
    for (int i = t; i < nodeN - node0; i += 256) cur[i] = offsets[node0 + i];
    __syncthreads();
    int jbeg = offsets[node0], jend = offsets[nodeN];
    for (int j = jbeg + t; j < jend; j += 256) {
        int2 r = stage[j];
        int slot = atomicAdd(&cur[r.x - node0], 1);
        adjw[slot] = r.y;
    }
}

// ---------------- row L2-normalize (F.normalize) ----------------
__global__ void k_normalize(const float* __restrict__ x, float* __restrict__ xn, int n) {
    int row  = (blockIdx.x * blockDim.x + threadIdx.x) >> 6;
    int lane = threadIdx.x & 63;
    if (row >= n) return;
    float v = x[row * DIM + lane];
    float s = v * v;
    #pragma unroll
    for (int off = 32; off; off >>= 1) s += __shfl_xor(s, off);
    float scale = 1.0f / fmaxf(sqrtf(s), 1e-12f);
    xn[row * DIM + lane] = v * scale;
}

// ---------------- CSR gather ----------------
// dst[d] = dinv[d] * ( sum_j dinv[adj_j]*src[adj_j]  +  dinv[d]*src[d] )
__global__ void k_gather(const int* __restrict__ adj, const int* __restrict__ offsets,
                         const float* __restrict__ dinv, const float* __restrict__ src,
                         float* __restrict__ dst, int n) {
    int w    = (blockIdx.x * blockDim.x + threadIdx.x) >> 6;  // wave per node
    int lane = threadIdx.x & 63;
    if (w >= n) return;
    int beg = offsets[w], end = offsets[w + 1];
    float dd = dinv[w];
    float selfv = src[(size_t)w * DIM + lane];
    float acc = 0.f;
    int j = beg;
    for (; j + 4 <= end; j += 4) {
        int s0 = adj[j], s1 = adj[j + 1], s2 = adj[j + 2], s3 = adj[j + 3];
        float d0 = dinv[s0], d1 = dinv[s1], d2 = dinv[s2], d3 = dinv[s3];
        float v0 = src[(size_t)s0 * DIM + lane];
        float v1 = src[(size_t)s1 * DIM + lane];
        float v2 = src[(size_t)s2 * DIM + lane];
        float v3 = src[(size_t)s3 * DIM + lane];
        acc = fmaf(d0, v0, acc);
        acc = fmaf(d1, v1, acc);
        acc = fmaf(d2, v2, acc);
        acc = fmaf(d3, v3, acc);
    }
    for (; j < end; ++j) {
        int s = adj[j];
        acc = fmaf(dinv[s], src[(size_t)s * DIM + lane], acc);
    }
    dst[(size_t)w * DIM + lane] = dd * (acc + dd * selfv);
}

// ---------------- register-tiled linear: out = [lrelu](in @ W^T + b) ----------------
__global__ __launch_bounds__(256) void k_linear_rt(
    const float* __restrict__ in, const float* __restrict__ W,
    const float* __restrict__ b, float* __restrict__ out,
    int n, int apply_lrelu)
{
    __shared__ float sIn[64][65];
    __shared__ float sW[64][65];
    int tid = threadIdx.x;
    int r0  = blockIdx.x * 64;
    #pragma unroll
    for (int i = 0; i < 16; i++) {
        int idx = tid + i * 256;
        sW[idx >> 6][idx & 63] = W[idx];
    }
    int lim = (n - r0 < 64 ? n - r0 : 64) * DIM;
    for (int idx = tid; idx < lim; idx += 256)
        sIn[idx >> 6][idx & 63] = in[(size_t)r0 * DIM + idx];
    __syncthreads();

    int ri = (tid >> 4) << 2;
    int ci = (tid & 15) << 2;
    float acc[4][4];
    #pragma unroll
    for (int j = 0; j < 4; j++) {
        float bj = b[ci + j];
        #pragma unroll
        for (int i = 0; i < 4; i++) acc[i][j] = bj;
    }
    #pragma unroll 4
    for (int k = 0; k < 64; k++) {
        float a0 = sIn[ri + 0][k], a1 = sIn[ri + 1][k];
        float a2 = sIn[ri + 2][k], a3 = sIn[ri + 3][k];
        float w0 = sW[ci + 0][k], w1 = sW[ci + 1][k];
        float w2 = sW[ci + 2][k], w3 = sW[ci + 3][k];
        acc[0][0] = fmaf(a0, w0, acc[0][0]); acc[0][1] = fmaf(a0, w1, acc[0][1]);
        acc[0][2] = fmaf(a0, w2, acc[0][2]); acc[0][3] = fmaf(a0, w3, acc[0][3]);
        acc[1][0] = fmaf(a1, w0, acc[1][0]); acc[1][1] = fmaf(a1, w1, acc[1][1]);
        acc[1][2] = fmaf(a1, w2, acc[1][2]); acc[1][3] = fmaf(a1, w3, acc[1][3]);
        acc[2][0] = fmaf(a2, w0, acc[2][0]); acc[2][1] = fmaf(a2, w1, acc[2][1]);
        acc[2][2] = fmaf(a2, w2, acc[2][2]); acc[2][3] = fmaf(a2, w3, acc[2][3]);
        acc[3][0] = fmaf(a3, w0, acc[3][0]); acc[3][1] = fmaf(a3, w1, acc[3][1]);
        acc[3][2] = fmaf(a3, w2, acc[3][2]); acc[3][3] = fmaf(a3, w3, acc[3][3]);
    }
    #pragma unroll
    for (int i = 0; i < 4; i++) {
        int r = r0 + ri + i;
        if (r >= n) break;
        float4 o;
        o.x = acc[i][0]; o.y = acc[i][1]; o.z = acc[i][2]; o.w = acc[i][3];
        if (apply_lrelu) {
            o.x = o.x > 0.f ? o.x : NEG_SLOPE * o.x;
            o.y = o.y > 0.f ? o.y : NEG_SLOPE * o.y;
            o.z = o.z > 0.f ? o.z : NEG_SLOPE * o.z;
            o.w = o.w > 0.f ? o.w : NEG_SLOPE * o.w;
        }
        *(float4*)&out[(size_t)r * DIM + ci] = o;
    }
}

// ---------------- final: out = xn + x1 + lrelu(agg@W2^T+b2) + (agg@W3^T+b3) ----------------
__global__ __launch_bounds__(256) void k_final_rt(
    const float* __restrict__ agg, const float* __restrict__ xn,
    const float* __restrict__ x1,
    const float* __restrict__ W2, const float* __restrict__ b2,
    const float* __restrict__ W3, const float* __restrict__ b3,
    float* __restrict__ out, int n)
{
    __shared__ float sIn[64][65];
    __shared__ float sW2[64][65];
    __shared__ float sW3[64][65];
    int tid = threadIdx.x;
    int r0  = blockIdx.x * 64;
    #pragma unroll
    for (int i = 0; i < 16; i++) {
        int idx = tid + i * 256;
        sW2[idx >> 6][idx & 63] = W2[idx];
        sW3[idx >> 6][idx & 63] = W3[idx];
    }
    int lim = (n - r0 < 64 ? n - r0 : 64) * DIM;
    for (int idx = tid; idx < lim; idx += 256)
        sIn[idx >> 6][idx & 63] = agg[(size_t)r0 * DIM + idx];
    __syncthreads();

    int ri = (tid >> 4) << 2;
    int ci = (tid & 15) << 2;
    float acc2[4][4], acc3[4][4];
    #pragma unroll
    for (int j = 0; j < 4; j++) {
        float bj2 = b2[ci + j], bj3 = b3[ci + j];
        #pragma unroll
        for (int i = 0; i < 4; i++) { acc2[i][j] = bj2; acc3[i][j] = bj3; }
    }
    #pragma unroll 2
    for (int k = 0; k < 64; k++) {
        float a0 = sIn[ri + 0][k], a1 = sIn[ri + 1][k];
        float a2 = sIn[ri + 2][k], a3 = sIn[ri + 3][k];
        float u0 = sW2[ci + 0][k], u1 = sW2[ci + 1][k];
        float u2 = sW2[ci + 2][k], u3 = sW2[ci + 3][k];
        float v0 = sW3[ci + 0][k], v1 = sW3[ci + 1][k];
        float v2 = sW3[ci + 2][k], v3 = sW3[ci + 3][k];
        acc2[0][0] = fmaf(a0, u0, acc2[0][0]); acc2[0][1] = fmaf(a0, u1, acc2[0][1]);
        acc2[0][2] = fmaf(a0, u2, acc2[0][2]); acc2[0][3] = fmaf(a0, u3, acc2[0][3]);
        acc2[1][0] = fmaf(a1, u0, acc2[1][0]); acc2[1][1] = fmaf(a1, u1, acc2[1][1]);
        acc2[1][2] = fmaf(a1, u2, acc2[1][2]); acc2[1][3] = fmaf(a1, u3, acc2[1][3]);
        acc2[2][0] = fmaf(a2, u0, acc2[2][0]); acc2[2][1] = fmaf(a2, u1, acc2[2][1]);
        acc2[2][2] = fmaf(a2, u2, acc2[2][2]); acc2[2][3] = fmaf(a2, u3, acc2[2][3]);
        acc2[3][0] = fmaf(a3, u0, acc2[3][0]); acc2[3][1] = fmaf(a3, u1, acc2[3][1]);
        acc2[3][2] = fmaf(a3, u2, acc2[3][2]); acc2[3][3] = fmaf(a3, u3, acc2[3][3]);
        acc3[0][0] = fmaf(a0, v0, acc3[0][0]); acc3[0][1] = fmaf(a0, v1, acc3[0][1]);
        acc3[0][2] = fmaf(a0, v2, acc3[0][2]); acc3[0][3] = fmaf(a0, v3, acc3[0][3]);
        acc3[1][0] = fmaf(a1, v0, acc3[1][0]); acc3[1][1] = fmaf(a1, v1, acc3[1][1]);
        acc3[1][2] = fmaf(a1, v2, acc3[1][2]); acc3[1][3] = fmaf(a1, v3, acc3[1][3]);
        acc3[2][0] = fmaf(a2, v0, acc3[2][0]); acc3[2][1] = fmaf(a2, v1, acc3[2][1]);
        acc3[2][2] = fmaf(a2, v2, acc3[2][2]); acc3[2][3] = fmaf(a2, v3, acc3[2][3]);
        acc3[3][0] = fmaf(a3, v0, acc3[3][0]); acc3[3][1] = fmaf(a3, v1, acc3[3][1]);
        acc3[3][2] = fmaf(a3, v2, acc3[3][2]); acc3[3][3] = fmaf(a3, v3, acc3[3][3]);
    }
    #pragma unroll
    for (int i = 0; i < 4; i++) {
        int r = r0 + ri + i;
        if (r >= n) break;
        size_t base = (size_t)r * DIM + ci;
        float4 vxn = *(const float4*)&xn[base];
        float4 vx1 = *(const float4*)&x1[base];
        float4 o;
        float e0 = acc2[i][0] > 0.f ? acc2[i][0] : NEG_SLOPE * acc2[i][0];
        float e1 = acc2[i][1] > 0.f ? acc2[i][1] : NEG_SLOPE * acc2[i][1];
        float e2 = acc2[i][2] > 0.f ? acc2[i][2] : NEG_SLOPE * acc2[i][2];
        float e3 = acc2[i][3] > 0.f ? acc2[i][3] : NEG_SLOPE * acc2[i][3];
        o.x = vxn.x + vx1.x + e0 + acc3[i][0];
        o.y = vxn.y + vx1.y + e1 + acc3[i][1];
        o.z = vxn.z + vx1.z + e2 + acc3[i][2];
        o.w = vxn.w + vx1.w + e3 + acc3[i][3];
        *(float4*)&out[base] = o;
    }
}

// ---------------- launcher ----------------

extern "C" void kernel_launch(void* const* d_in, const int* in_sizes, int n_in,
                              void* d_out, int out_size, void* d_ws, size_t ws_size,
                              hipStream_t stream) {
    const int*   ei  = (const int*)d_in[0];
    const float* emb = (const float*)d_in[1];
    const float* W1  = (const float*)d_in[2];
    const float* b1  = (const float*)d_in[3];
    const float* W2  = (const float*)d_in[4];
    const float* b2  = (const float*)d_in[5];
    const float* W3  = (const float*)d_in[6];
    const float* b3  = (const float*)d_in[7];
    float* out = (float*)d_out;

    int E = in_sizes[0] / 2;
    int n = in_sizes[1] / DIM;
    size_t nD = (size_t)n * DIM;

    // bucket shift: <=256 buckets, span<=2048 (n<=524288)
    int shift = 9;
    while ((((size_t)n + ((size_t)1 << shift) - 1) >> shift) > 256) shift++;
    int nbuckets = (int)(((size_t)n + ((size_t)1 << shift) - 1) >> shift);

    // workspace layout (all regions fully initialized each call)
    size_t np = ((size_t)n + 1023) & ~1023ull;
    int*   degi    = (int*)d_ws;              // np ints
    int*   offsets = degi + np;               // np ints (n+1 used)
    int*   bsums   = offsets + np;            // 1024
    int*   bcur    = bsums + 1024;            // 256
    float* dinv    = (float*)(bcur + 256);    // np
    float* xn      = dinv + np;               // nD
    float* x1      = xn + nD;                 // nD
    float* agg     = x1 + nD;                 // nD (aliases stage: 2E*2 <= nD*? ok here)
    int*   adjw    = (int*)(agg + nD);        // 2E ints
    int2*  stage   = (int2*)agg;              // 2E int2, dead before first k_gather

    const int B = 256;
    int nb = (n + 1023) / 1024;

    // --- degree + scan ---
    k_zero_i32 <<<(n + B - 1) / B, B, 0, stream>>>(degi, n);
    k_deg_count<<<(E + B - 1) / B, B, 0, stream>>>(ei, E, degi);
    k_dinv     <<<(n + B - 1) / B, B, 0, stream>>>(degi, dinv, n);
    k_scanA    <<<nb, B, 0, stream>>>(degi, n, bsums);
    k_scanB    <<<1, B, 0, stream>>>(bsums, nb, offsets, n);
    k_scanC    <<<nb, B, 0, stream>>>(degi, n, bsums, offsets);

    // --- binned CSR build ---
    k_bcur_init<<<1, B, 0, stream>>>(offsets, bcur, shift, nbuckets);
    k_bin      <<<(E + EPW - 1) / EPW, B, 0, stream>>>(ei, E, stage, bcur, shift);
    k_bsort    <<<nbuckets, B, 0, stream>>>(stage, offsets, adjw, n, shift);

    // --- xn = row-L2-normalized embedding ---
    k_normalize<<<(n + 3) / 4, B, 0, stream>>>(emb, xn, n);

    // --- layer 1 ---
    k_gather   <<<(n + 3) / 4, B, 0, stream>>>(adjw, offsets, dinv, xn, agg, n);
    k_linear_rt<<<(n + 63) / 64, B, 0, stream>>>(agg, W1, b1, x1, n, 1);

    // --- layers 2+3 fused ---
    k_gather   <<<(n + 3) / 4, B, 0, stream>>>(adjw, offsets, dinv, x1, agg, n);
    k_final_rt <<<(n + 63) / 64, B, 0, stream>>>(agg, xn, x1, W2, b2, W3, b3, out, n);
}

// Round 5
// 362.117 us; speedup vs baseline: 3.1874x; 1.0670x over previous
//
#include <hip/hip_runtime.h>
#include <math.h>

#define DIM 64
#define NEG_SLOPE 0.01f

typedef unsigned short bfraw;

__device__ __forceinline__ bfraw f2bf(float f) {
    unsigned int u = __float_as_uint(f);
    unsigned int r = (u + 0x7FFFu + ((u >> 16) & 1u)) >> 16;  // RNE
    return (bfraw)r;
}
__device__ __forceinline__ float bf2f(bfraw h) {
    return __uint_as_float(((unsigned int)h) << 16);
}

// ---------------- small utility ----------------

__global__ void k_zero_i32(int* __restrict__ p, int n) {
    int i = blockIdx.x * blockDim.x + threadIdx.x;
    if (i < n) p[i] = 0;
}

__global__ void k_deg_count(const int* __restrict__ ei, int E, int* __restrict__ degi) {
    int e = blockIdx.x * blockDim.x + threadIdx.x;
    if (e < E) {
        atomicAdd(degi + ei[e], 1);
        atomicAdd(degi + ei[E + e], 1);
    }
}

__global__ void k_dinv(const int* __restrict__ degi, float* __restrict__ dinv, int n) {
    int i = blockIdx.x * blockDim.x + threadIdx.x;
    if (i < n) dinv[i] = rsqrtf(1.0f + (float)degi[i]);
}

// ---------------- exclusive scan of degi -> offsets ----------------
__global__ void k_scanA(const int* __restrict__ degi, int n, int* __restrict__ bsums) {
    __shared__ int ls[256];
    int t = threadIdx.x;
    int base = blockIdx.x * 1024 + t * 4;
    int s = 0;
    #pragma unroll
    for (int k = 0; k < 4; k++) { int i = base + k; if (i < n) s += degi[i]; }
    ls[t] = s; __syncthreads();
    for (int off = 128; off; off >>= 1) {
        if (t < off) ls[t] += ls[t + off];
        __syncthreads();
    }
    if (t == 0) bsums[blockIdx.x] = ls[0];
}

__global__ void k_scanB(int* __restrict__ bsums, int nb, int* __restrict__ offsets, int n) {
    __shared__ int ls[1024];
    int t = threadIdx.x;
    for (int i = t; i < nb; i += 256) ls[i] = bsums[i];
    __syncthreads();
    if (t == 0) {
        int run = 0;
        for (int i = 0; i < nb; i++) { int v = ls[i]; ls[i] = run; run += v; }
        offsets[n] = run;
    }
    __syncthreads();
    for (int i = t; i < nb; i += 256) bsums[i] = ls[i];
}

__global__ void k_scanC(const int* __restrict__ degi, int n, const int* __restrict__ bsums,
                        int* __restrict__ offsets) {
    __shared__ int ls[256];
    int t = threadIdx.x;
    int base = blockIdx.x * 1024 + t * 4;
    int a[4]; int s = 0;
    #pragma unroll
    for (int k = 0; k < 4; k++) { int i = base + k; a[k] = (i < n) ? degi[i] : 0; s += a[k]; }
    ls[t] = s; __syncthreads();
    for (int off = 1; off < 256; off <<= 1) {
        int v = (t >= off) ? ls[t - off] : 0;
        __syncthreads();
        ls[t] += v;
        __syncthreads();
    }
    int run = bsums[blockIdx.x] + ls[t] - s;
    #pragma unroll
    for (int k = 0; k < 4; k++) {
        int i = base + k;
        if (i < n) offsets[i] = run;
        run += a[k];
    }
}

// ---------------- binned CSR build ----------------
__global__ void k_bcur_init(const int* __restrict__ offsets, int* __restrict__ bcur,
                            int shift, int nbuckets) {
    int b = blockIdx.x * blockDim.x + threadIdx.x;
    if (b < nbuckets) bcur[b] = offsets[(size_t)b << shift];
}

#define EPW 2048

__global__ __launch_bounds__(256) void k_bin(const int* __restrict__ ei, int E,
                                             int2* __restrict__ stage,
                                             int* __restrict__ bcur, int shift) {
    __shared__ int hist[256];
    __shared__ int cur[256];
    int t = threadIdx.x;
    hist[t] = 0;
    __syncthreads();
    int e0 = blockIdx.x * EPW;
    int e1 = e0 + EPW < E ? e0 + EPW : E;
    for (int e = e0 + t; e < e1; e += 256) {
        int u = ei[e], v = ei[E + e];
        atomicAdd(&hist[u >> shift], 1);
        atomicAdd(&hist[v >> shift], 1);
    }
    __syncthreads();
    cur[t] = hist[t] > 0 ? atomicAdd(&bcur[t], hist[t]) : 0;
    __syncthreads();
    for (int e = e0 + t; e < e1; e += 256) {
        int u = ei[e], v = ei[E + e];
        int s1 = atomicAdd(&cur[v >> shift], 1);
        stage[s1] = make_int2(v, u);
        int s2 = atomicAdd(&cur[u >> shift], 1);
        stage[s2] = make_int2(u, v);
    }
}

__global__ __launch_bounds__(256) void k_bsort(const int2* __restrict__ stage,
                                               const int* __restrict__ offsets,
                                               int* __restrict__ adjw, int n, int shift) {
    __shared__ int cur[2048];
    int t = threadIdx.x;
    int span  = 1 << shift;
    int node0 = blockIdx.x << shift;
    int nodeN = node0 + span < n ? node0 + span : n;
    for (int i = t; i < nodeN - node0; i += 256) cur[i] = offsets[node0 + i];
    __syncthreads();
    int jbeg = offsets[node0], jend = offsets[nodeN];
    for (int j = jbeg + t; j < jend; j += 256) {
        int2 r = stage[j];
        int slot = atomicAdd(&cur[r.x - node0], 1);
        adjw[slot] = r.y;
    }
}

// ---------------- row L2-normalize + prescaled bf16 copy ----------------
__global__ void k_normalize(const float* __restrict__ x, const float* __restrict__ dinv,
                            float* __restrict__ xn, bfraw* __restrict__ xnw, int n) {
    int row  = (blockIdx.x * blockDim.x + threadIdx.x) >> 6;
    int lane = threadIdx.x & 63;
    if (row >= n) return;
    float v = x[row * DIM + lane];
    float s = v * v;
    #pragma unroll
    for (int off = 32; off; off >>= 1) s += __shfl_xor(s, off);
    float scale = 1.0f / fmaxf(sqrtf(s), 1e-12f);
    float xv = v * scale;
    xn[row * DIM + lane] = xv;
    xnw[row * DIM + lane] = f2bf(xv * dinv[row]);
}

// ---------------- CSR gather (bf16 prescaled rows) ----------------
// dst[d] = dinv[d] * ( sum_j srcw[adj_j]  +  dinv[d]*src[d] ),  srcw = bf16(dinv*src)
__global__ void k_gather(const int* __restrict__ adj, const int* __restrict__ offsets,
                         const float* __restrict__ dinv,
                         const bfraw* __restrict__ srcw, const float* __restrict__ src,
                         float* __restrict__ dst, int n) {
    int w    = (blockIdx.x * blockDim.x + threadIdx.x) >> 6;  // wave per node
    int lane = threadIdx.x & 63;
    if (w >= n) return;
    int beg = offsets[w], end = offsets[w + 1];
    float dd = dinv[w];
    float selfv = src[(size_t)w * DIM + lane];
    float acc = 0.f;
    int j = beg;
    for (; j + 8 <= end; j += 8) {
        int s0 = adj[j],     s1 = adj[j + 1], s2 = adj[j + 2], s3 = adj[j + 3];
        int s4 = adj[j + 4], s5 = adj[j + 5], s6 = adj[j + 6], s7 = adj[j + 7];
        float v0 = bf2f(srcw[(size_t)s0 * DIM + lane]);
        float v1 = bf2f(srcw[(size_t)s1 * DIM + lane]);
        float v2 = bf2f(srcw[(size_t)s2 * DIM + lane]);
        float v3 = bf2f(srcw[(size_t)s3 * DIM + lane]);
        float v4 = bf2f(srcw[(size_t)s4 * DIM + lane]);
        float v5 = bf2f(srcw[(size_t)s5 * DIM + lane]);
        float v6 = bf2f(srcw[(size_t)s6 * DIM + lane]);
        float v7 = bf2f(srcw[(size_t)s7 * DIM + lane]);
        acc += ((v0 + v1) + (v2 + v3)) + ((v4 + v5) + (v6 + v7));
    }
    for (; j < end; ++j) {
        acc += bf2f(srcw[(size_t)adj[j] * DIM + lane]);
    }
    dst[(size_t)w * DIM + lane] = dd * (acc + dd * selfv);
}

// ---------------- register-tiled linear: x1 = lrelu(in @ W^T + b), + bf16 prescaled copy ----------------
__global__ __launch_bounds__(256) void k_linear_rt(
    const float* __restrict__ in, const float* __restrict__ W,
    const float* __restrict__ b, const float* __restrict__ dinv,
    float* __restrict__ out, bfraw* __restrict__ outw, int n)
{
    __shared__ float sIn[64][65];
    __shared__ float sW[64][65];
    int tid = threadIdx.x;
    int r0  = blockIdx.x * 64;
    #pragma unroll
    for (int i = 0; i < 16; i++) {
        int idx = tid + i * 256;
        sW[idx >> 6][idx & 63] = W[idx];
    }
    int lim = (n - r0 < 64 ? n - r0 : 64) * DIM;
    for (int idx = tid; idx < lim; idx += 256)
        sIn[idx >> 6][idx & 63] = in[(size_t)r0 * DIM + idx];
    __syncthreads();

    int ri = (tid >> 4) << 2;
    int ci = (tid & 15) << 2;
    float acc[4][4];
    #pragma unroll
    for (int j = 0; j < 4; j++) {
        float bj = b[ci + j];
        #pragma unroll
        for (int i = 0; i < 4; i++) acc[i][j] = bj;
    }
    #pragma unroll 4
    for (int k = 0; k < 64; k++) {
        float a0 = sIn[ri + 0][k], a1 = sIn[ri + 1][k];
        float a2 = sIn[ri + 2][k], a3 = sIn[ri + 3][k];
        float w0 = sW[ci + 0][k], w1 = sW[ci + 1][k];
        float w2 = sW[ci + 2][k], w3 = sW[ci + 3][k];
        acc[0][0] = fmaf(a0, w0, acc[0][0]); acc[0][1] = fmaf(a0, w1, acc[0][1]);
        acc[0][2] = fmaf(a0, w2, acc[0][2]); acc[0][3] = fmaf(a0, w3, acc[0][3]);
        acc[1][0] = fmaf(a1, w0, acc[1][0]); acc[1][1] = fmaf(a1, w1, acc[1][1]);
        acc[1][2] = fmaf(a1, w2, acc[1][2]); acc[1][3] = fmaf(a1, w3, acc[1][3]);
        acc[2][0] = fmaf(a2, w0, acc[2][0]); acc[2][1] = fmaf(a2, w1, acc[2][1]);
        acc[2][2] = fmaf(a2, w2, acc[2][2]); acc[2][3] = fmaf(a2, w3, acc[2][3]);
        acc[3][0] = fmaf(a3, w0, acc[3][0]); acc[3][1] = fmaf(a3, w1, acc[3][1]);
        acc[3][2] = fmaf(a3, w2, acc[3][2]); acc[3][3] = fmaf(a3, w3, acc[3][3]);
    }
    #pragma unroll
    for (int i = 0; i < 4; i++) {
        int r = r0 + ri + i;
        if (r >= n) break;
        float dd = dinv[r];
        float4 o;
        o.x = acc[i][0] > 0.f ? acc[i][0] : NEG_SLOPE * acc[i][0];
        o.y = acc[i][1] > 0.f ? acc[i][1] : NEG_SLOPE * acc[i][1];
        o.z = acc[i][2] > 0.f ? acc[i][2] : NEG_SLOPE * acc[i][2];
        o.w = acc[i][3] > 0.f ? acc[i][3] : NEG_SLOPE * acc[i][3];
        *(float4*)&out[(size_t)r * DIM + ci] = o;
        ushort4 ow;
        ow.x = f2bf(o.x * dd); ow.y = f2bf(o.y * dd);
        ow.z = f2bf(o.z * dd); ow.w = f2bf(o.w * dd);
        *(ushort4*)&outw[(size_t)r * DIM + ci] = ow;
    }
}

// ---------------- final: out = xn + x1 + lrelu(agg@W2^T+b2) + (agg@W3^T+b3) ----------------
__global__ __launch_bounds__(256) void k_final_rt(
    const float* __restrict__ agg, const float* __restrict__ xn,
    const float* __restrict__ x1,
    const float* __restrict__ W2, const float* __restrict__ b2,
    const float* __restrict__ W3, const float* __restrict__ b3,
    float* __restrict__ out, int n)
{
    __shared__ float sIn[64][65];
    __shared__ float sW2[64][65];
    __shared__ float sW3[64][65];
    int tid = threadIdx.x;
    int r0  = blockIdx.x * 64;
    #pragma unroll
    for (int i = 0; i < 16; i++) {
        int idx = tid + i * 256;
        sW2[idx >> 6][idx & 63] = W2[idx];
        sW3[idx >> 6][idx & 63] = W3[idx];
    }
    int lim = (n - r0 < 64 ? n - r0 : 64) * DIM;
    for (int idx = tid; idx < lim; idx += 256)
        sIn[idx >> 6][idx & 63] = agg[(size_t)r0 * DIM + idx];
    __syncthreads();

    int ri = (tid >> 4) << 2;
    int ci = (tid & 15) << 2;
    float acc2[4][4], acc3[4][4];
    #pragma unroll
    for (int j = 0; j < 4; j++) {
        float bj2 = b2[ci + j], bj3 = b3[ci + j];
        #pragma unroll
        for (int i = 0; i < 4; i++) { acc2[i][j] = bj2; acc3[i][j] = bj3; }
    }
    #pragma unroll 2
    for (int k = 0; k < 64; k++) {
        float a0 = sIn[ri + 0][k], a1 = sIn[ri + 1][k];
        float a2 = sIn[ri + 2][k], a3 = sIn[ri + 3][k];
        float u0 = sW2[ci + 0][k], u1 = sW2[ci + 1][k];
        float u2 = sW2[ci + 2][k], u3 = sW2[ci + 3][k];
        float v0 = sW3[ci + 0][k], v1 = sW3[ci + 1][k];
        float v2 = sW3[ci + 2][k], v3 = sW3[ci + 3][k];
        acc2[0][0] = fmaf(a0, u0, acc2[0][0]); acc2[0][1] = fmaf(a0, u1, acc2[0][1]);
        acc2[0][2] = fmaf(a0, u2, acc2[0][2]); acc2[0][3] = fmaf(a0, u3, acc2[0][3]);
        acc2[1][0] = fmaf(a1, u0, acc2[1][0]); acc2[1][1] = fmaf(a1, u1, acc2[1][1]);
        acc2[1][2] = fmaf(a1, u2, acc2[1][2]); acc2[1][3] = fmaf(a1, u3, acc2[1][3]);
        acc2[2][0] = fmaf(a2, u0, acc2[2][0]); acc2[2][1] = fmaf(a2, u1, acc2[2][1]);
        acc2[2][2] = fmaf(a2, u2, acc2[2][2]); acc2[2][3] = fmaf(a2, u3, acc2[2][3]);
        acc2[3][0] = fmaf(a3, u0, acc2[3][0]); acc2[3][1] = fmaf(a3, u1, acc2[3][1]);
        acc2[3][2] = fmaf(a3, u2, acc2[3][2]); acc2[3][3] = fmaf(a3, u3, acc2[3][3]);
        acc3[0][0] = fmaf(a0, v0, acc3[0][0]); acc3[0][1] = fmaf(a0, v1, acc3[0][1]);
        acc3[0][2] = fmaf(a0, v2, acc3[0][2]); acc3[0][3] = fmaf(a0, v3, acc3[0][3]);
        acc3[1][0] = fmaf(a1, v0, acc3[1][0]); acc3[1][1] = fmaf(a1, v1, acc3[1][1]);
        acc3[1][2] = fmaf(a1, v2, acc3[1][2]); acc3[1][3] = fmaf(a1, v3, acc3[1][3]);
        acc3[2][0] = fmaf(a2, v0, acc3[2][0]); acc3[2][1] = fmaf(a2, v1, acc3[2][1]);
        acc3[2][2] = fmaf(a2, v2, acc3[2][2]); acc3[2][3] = fmaf(a2, v3, acc3[2][3]);
        acc3[3][0] = fmaf(a3, v0, acc3[3][0]); acc3[3][1] = fmaf(a3, v1, acc3[3][1]);
        acc3[3][2] = fmaf(a3, v2, acc3[3][2]); acc3[3][3] = fmaf(a3, v3, acc3[3][3]);
    }
    #pragma unroll
    for (int i = 0; i < 4; i++) {
        int r = r0 + ri + i;
        if (r >= n) break;
        size_t base = (size_t)r * DIM + ci;
        float4 vxn = *(const float4*)&xn[base];
        float4 vx1 = *(const float4*)&x1[base];
        float4 o;
        float e0 = acc2[i][0] > 0.f ? acc2[i][0] : NEG_SLOPE * acc2[i][0];
        float e1 = acc2[i][1] > 0.f ? acc2[i][1] : NEG_SLOPE * acc2[i][1];
        float e2 = acc2[i][2] > 0.f ? acc2[i][2] : NEG_SLOPE * acc2[i][2];
        float e3 = acc2[i][3] > 0.f ? acc2[i][3] : NEG_SLOPE * acc2[i][3];
        o.x = vxn.x + vx1.x + e0 + acc3[i][0];
        o.y = vxn.y + vx1.y + e1 + acc3[i][1];
        o.z = vxn.z + vx1.z + e2 + acc3[i][2];
        o.w = vxn.w + vx1.w + e3 + acc3[i][3];
        *(float4*)&out[base] = o;
    }
}

// ---------------- launcher ----------------

extern "C" void kernel_launch(void* const* d_in, const int* in_sizes, int n_in,
                              void* d_out, int out_size, void* d_ws, size_t ws_size,
                              hipStream_t stream) {
    const int*   ei  = (const int*)d_in[0];
    const float* emb = (const float*)d_in[1];
    const float* W1  = (const float*)d_in[2];
    const float* b1  = (const float*)d_in[3];
    const float* W2  = (const float*)d_in[4];
    const float* b2  = (const float*)d_in[5];
    const float* W3  = (const float*)d_in[6];
    const float* b3  = (const float*)d_in[7];
    float* out = (float*)d_out;

    int E = in_sizes[0] / 2;
    int n = in_sizes[1] / DIM;
    size_t nD = (size_t)n * DIM;

    int shift = 9;
    while ((((size_t)n + ((size_t)1 << shift) - 1) >> shift) > 256) shift++;
    int nbuckets = (int)(((size_t)n + ((size_t)1 << shift) - 1) >> shift);

    // workspace layout (all regions fully initialized each call)
    size_t np = ((size_t)n + 1023) & ~1023ull;
    int*   degi    = (int*)d_ws;              // np ints
    int*   offsets = degi + np;               // np ints (n+1 used)
    int*   bsums   = offsets + np;            // 1024
    int*   bcur    = bsums + 1024;            // 256
    float* dinv    = (float*)(bcur + 256);    // np
    float* xn      = dinv + np;               // nD f32
    float* x1      = xn + nD;                 // nD f32
    float* agg     = x1 + nD;                 // nD f32 (stage aliases this)
    int*   adjw    = (int*)(agg + nD);        // 2E ints
    bfraw* xnw     = (bfraw*)(adjw + 2 * (size_t)E);  // nD bf16
    bfraw* x1w     = xnw + nD;                // nD bf16
    int2*  stage   = (int2*)agg;              // 2E int2, dead before first k_gather

    const int B = 256;
    int nb = (n + 1023) / 1024;

    // --- degree + scan ---
    k_zero_i32 <<<(n + B - 1) / B, B, 0, stream>>>(degi, n);
    k_deg_count<<<(E + B - 1) / B, B, 0, stream>>>(ei, E, degi);
    k_dinv     <<<(n + B - 1) / B, B, 0, stream>>>(degi, dinv, n);
    k_scanA    <<<nb, B, 0, stream>>>(degi, n, bsums);
    k_scanB    <<<1, B, 0, stream>>>(bsums, nb, offsets, n);
    k_scanC    <<<nb, B, 0, stream>>>(degi, n, bsums, offsets);

    // --- binned CSR build ---
    k_bcur_init<<<1, B, 0, stream>>>(offsets, bcur, shift, nbuckets);
    k_bin      <<<(E + EPW - 1) / EPW, B, 0, stream>>>(ei, E, stage, bcur, shift);
    k_bsort    <<<nbuckets, B, 0, stream>>>(stage, offsets, adjw, n, shift);

    // --- xn = row-L2-normalized embedding (+ prescaled bf16) ---
    k_normalize<<<(n + 3) / 4, B, 0, stream>>>(emb, dinv, xn, xnw, n);

    // --- layer 1 ---
    k_gather   <<<(n + 3) / 4, B, 0, stream>>>(adjw, offsets, dinv, xnw, xn, agg, n);
    k_linear_rt<<<(n + 63) / 64, B, 0, stream>>>(agg, W1, b1, dinv, x1, x1w, n);

    // --- layers 2+3 fused ---
    k_gather   <<<(n + 3) / 4, B, 0, stream>>>(adjw, offsets, dinv, x1w, x1, agg, n);
    k_final_rt <<<(n + 63) / 64, B, 0, stream>>>(agg, xn, x1, W2, b2, W3, b3, out, n);
}

// Round 6
// 291.612 us; speedup vs baseline: 3.9580x; 1.2418x over previous
//
#include <hip/hip_runtime.h>
#include <math.h>

#define DIM 64
#define NEG_SLOPE 0.01f

typedef unsigned short bfraw;

__device__ __forceinline__ bfraw f2bf(float f) {
    unsigned int u = __float_as_uint(f);
    unsigned int r = (u + 0x7FFFu + ((u >> 16) & 1u)) >> 16;  // RNE
    return (bfraw)r;
}
__device__ __forceinline__ float bf2f(bfraw h) {
    return __uint_as_float(((unsigned int)h) << 16);
}

// ---------------- small utility ----------------

__global__ void k_zero_i32(int* __restrict__ p, int n) {
    int i = blockIdx.x * blockDim.x + threadIdx.x;
    if (i < n) p[i] = 0;
}

// ---------------- bucket histogram (LDS-aggregated; bcnt stride-16 padded) ----------------
#define EPH 8192

__global__ __launch_bounds__(256) void k_bhist(const int* __restrict__ ei, int E,
                                               int* __restrict__ bcnt, int shift) {
    __shared__ int hist[256];
    int t = threadIdx.x;
    hist[t] = 0;
    __syncthreads();
    int e0 = blockIdx.x * EPH;
    int e1 = e0 + EPH < E ? e0 + EPH : E;
    for (int e = e0 + t; e < e1; e += 256) {
        int u = ei[e], v = ei[E + e];
        atomicAdd(&hist[u >> shift], 1);
        atomicAdd(&hist[v >> shift], 1);
    }
    __syncthreads();
    if (hist[t]) atomicAdd(&bcnt[t * 16], hist[t]);
}

// single WG: exclusive-scan bucket counts -> boffs[nbuckets+1], init bcur, offsets[n]
__global__ __launch_bounds__(256) void k_bscan(const int* __restrict__ bcnt, int nbuckets,
                                               int* __restrict__ boffs, int* __restrict__ bcur,
                                               int* __restrict__ offsets, int n, int E2) {
    __shared__ int ls[256];
    int t = threadIdx.x;
    int own = (t < nbuckets) ? bcnt[t * 16] : 0;
    ls[t] = own;
    __syncthreads();
    for (int off = 1; off < 256; off <<= 1) {
        int v = (t >= off) ? ls[t - off] : 0;
        __syncthreads();
        ls[t] += v;
        __syncthreads();
    }
    int excl = ls[t] - own;
    if (t < nbuckets) { boffs[t] = excl; bcur[t * 16] = excl; }
    if (t == 0) { boffs[nbuckets] = E2; offsets[n] = E2; }
}

// ---------------- bin records (dst,src) into bucket-contiguous stage ----------------
#define EPW 2048

__global__ __launch_bounds__(256) void k_bin(const int* __restrict__ ei, int E,
                                             int2* __restrict__ stage,
                                             int* __restrict__ bcur, int shift) {
    __shared__ int hist[256];
    __shared__ int cur[256];
    int t = threadIdx.x;
    hist[t] = 0;
    __syncthreads();
    int e0 = blockIdx.x * EPW;
    int e1 = e0 + EPW < E ? e0 + EPW : E;
    for (int e = e0 + t; e < e1; e += 256) {
        int u = ei[e], v = ei[E + e];
        atomicAdd(&hist[u >> shift], 1);
        atomicAdd(&hist[v >> shift], 1);
    }
    __syncthreads();
    cur[t] = hist[t] > 0 ? atomicAdd(&bcur[t * 16], hist[t]) : 0;
    __syncthreads();
    for (int e = e0 + t; e < e1; e += 256) {
        int u = ei[e], v = ei[E + e];
        int s1 = atomicAdd(&cur[v >> shift], 1);
        stage[s1] = make_int2(v, u);
        int s2 = atomicAdd(&cur[u >> shift], 1);
        stage[s2] = make_int2(u, v);
    }
}

// ---------------- per-bucket: degree count + local scan -> offsets/dinv, then place ----------------
__global__ __launch_bounds__(256) void k_bucket(const int2* __restrict__ stage,
                                                const int* __restrict__ boffs,
                                                int* __restrict__ offsets,
                                                int* __restrict__ adj,
                                                float* __restrict__ dinv,
                                                int n, int shift) {
    __shared__ int deg[2048];   // per-node degree, then reused as placement cursor
    __shared__ int scan[256];
    int t = threadIdx.x;
    int span  = 1 << shift;
    int node0 = blockIdx.x << shift;
    int cnt = n - node0 < span ? n - node0 : span;
    for (int i = t; i < cnt; i += 256) deg[i] = 0;
    __syncthreads();
    int jbeg = boffs[blockIdx.x], jend = boffs[blockIdx.x + 1];
    for (int j = jbeg + t; j < jend; j += 256)
        atomicAdd(&deg[stage[j].x - node0], 1);
    __syncthreads();
    // exclusive scan of deg[0..cnt): per-thread chunk + Hillis-Steele over thread sums
    int per  = span >> 8;          // elements per thread (span>=256)
    int base = t * per;
    int s = 0;
    for (int k = 0; k < per; k++) { int i = base + k; if (i < cnt) s += deg[i]; }
    scan[t] = s;
    __syncthreads();
    for (int off = 1; off < 256; off <<= 1) {
        int v = (t >= off) ? scan[t - off] : 0;
        __syncthreads();
        scan[t] += v;
        __syncthreads();
    }
    int run = jbeg + scan[t] - s;  // global exclusive offset for this thread's first node
    for (int k = 0; k < per; k++) {
        int i = base + k;
        if (i < cnt) {
            int d = deg[i];
            offsets[node0 + i] = run;
            dinv[node0 + i] = rsqrtf(1.0f + (float)d);
            deg[i] = run;          // becomes placement cursor (own index only: safe)
            run += d;
        }
    }
    __syncthreads();
    for (int j = jbeg + t; j < jend; j += 256) {
        int2 r = stage[j];
        int slot = atomicAdd(&deg[r.x - node0], 1);
        adj[slot] = r.y;
    }
}

// ---------------- row L2-normalize + prescaled bf16 copy ----------------
__global__ void k_normalize(const float* __restrict__ x, const float* __restrict__ dinv,
                            float* __restrict__ xn, bfraw* __restrict__ xnw, int n) {
    int row  = (blockIdx.x * blockDim.x + threadIdx.x) >> 6;
    int lane = threadIdx.x & 63;
    if (row >= n) return;
    float v = x[row * DIM + lane];
    float s = v * v;
    #pragma unroll
    for (int off = 32; off; off >>= 1) s += __shfl_xor(s, off);
    float scale = 1.0f / fmaxf(sqrtf(s), 1e-12f);
    float xv = v * scale;
    xn[row * DIM + lane] = xv;
    xnw[row * DIM + lane] = f2bf(xv * dinv[row]);
}

// ---------------- CSR gather (bf16 prescaled rows) ----------------
// dst[d] = dinv[d] * ( sum_j srcw[adj_j]  +  dinv[d]*src[d] ),  srcw = bf16(dinv*src)
__global__ void k_gather(const int* __restrict__ adj, const int* __restrict__ offsets,
                         const float* __restrict__ dinv,
                         const bfraw* __restrict__ srcw, const float* __restrict__ src,
                         float* __restrict__ dst, int n) {
    int w    = (blockIdx.x * blockDim.x + threadIdx.x) >> 6;  // wave per node
    int lane = threadIdx.x & 63;
    if (w >= n) return;
    int beg = offsets[w], end = offsets[w + 1];
    float dd = dinv[w];
    float selfv = src[(size_t)w * DIM + lane];
    float acc = 0.f;
    int j = beg;
    for (; j + 8 <= end; j += 8) {
        int s0 = adj[j],     s1 = adj[j + 1], s2 = adj[j + 2], s3 = adj[j + 3];
        int s4 = adj[j + 4], s5 = adj[j + 5], s6 = adj[j + 6], s7 = adj[j + 7];
        float v0 = bf2f(srcw[(size_t)s0 * DIM + lane]);
        float v1 = bf2f(srcw[(size_t)s1 * DIM + lane]);
        float v2 = bf2f(srcw[(size_t)s2 * DIM + lane]);
        float v3 = bf2f(srcw[(size_t)s3 * DIM + lane]);
        float v4 = bf2f(srcw[(size_t)s4 * DIM + lane]);
        float v5 = bf2f(srcw[(size_t)s5 * DIM + lane]);
        float v6 = bf2f(srcw[(size_t)s6 * DIM + lane]);
        float v7 = bf2f(srcw[(size_t)s7 * DIM + lane]);
        acc += ((v0 + v1) + (v2 + v3)) + ((v4 + v5) + (v6 + v7));
    }
    for (; j < end; ++j) {
        acc += bf2f(srcw[(size_t)adj[j] * DIM + lane]);
    }
    dst[(size_t)w * DIM + lane] = dd * (acc + dd * selfv);
}

// ---------------- register-tiled linear: x1 = lrelu(in @ W^T + b), + bf16 prescaled copy ----------------
__global__ __launch_bounds__(256) void k_linear_rt(
    const float* __restrict__ in, const float* __restrict__ W,
    const float* __restrict__ b, const float* __restrict__ dinv,
    float* __restrict__ out, bfraw* __restrict__ outw, int n)
{
    __shared__ float sIn[64][65];
    __shared__ float sW[64][65];
    int tid = threadIdx.x;
    int r0  = blockIdx.x * 64;
    #pragma unroll
    for (int i = 0; i < 16; i++) {
        int idx = tid + i * 256;
        sW[idx >> 6][idx & 63] = W[idx];
    }
    int lim = (n - r0 < 64 ? n - r0 : 64) * DIM;
    for (int idx = tid; idx < lim; idx += 256)
        sIn[idx >> 6][idx & 63] = in[(size_t)r0 * DIM + idx];
    __syncthreads();

    int ri = (tid >> 4) << 2;
    int ci = (tid & 15) << 2;
    float acc[4][4];
    #pragma unroll
    for (int j = 0; j < 4; j++) {
        float bj = b[ci + j];
        #pragma unroll
        for (int i = 0; i < 4; i++) acc[i][j] = bj;
    }
    #pragma unroll 4
    for (int k = 0; k < 64; k++) {
        float a0 = sIn[ri + 0][k], a1 = sIn[ri + 1][k];
        float a2 = sIn[ri + 2][k], a3 = sIn[ri + 3][k];
        float w0 = sW[ci + 0][k], w1 = sW[ci + 1][k];
        float w2 = sW[ci + 2][k], w3 = sW[ci + 3][k];
        acc[0][0] = fmaf(a0, w0, acc[0][0]); acc[0][1] = fmaf(a0, w1, acc[0][1]);
        acc[0][2] = fmaf(a0, w2, acc[0][2]); acc[0][3] = fmaf(a0, w3, acc[0][3]);
        acc[1][0] = fmaf(a1, w0, acc[1][0]); acc[1][1] = fmaf(a1, w1, acc[1][1]);
        acc[1][2] = fmaf(a1, w2, acc[1][2]); acc[1][3] = fmaf(a1, w3, acc[1][3]);
        acc[2][0] = fmaf(a2, w0, acc[2][0]); acc[2][1] = fmaf(a2, w1, acc[2][1]);
        acc[2][2] = fmaf(a2, w2, acc[2][2]); acc[2][3] = fmaf(a2, w3, acc[2][3]);
        acc[3][0] = fmaf(a3, w0, acc[3][0]); acc[3][1] = fmaf(a3, w1, acc[3][1]);
        acc[3][2] = fmaf(a3, w2, acc[3][2]); acc[3][3] = fmaf(a3, w3, acc[3][3]);
    }
    #pragma unroll
    for (int i = 0; i < 4; i++) {
        int r = r0 + ri + i;
        if (r >= n) break;
        float dd = dinv[r];
        float4 o;
        o.x = acc[i][0] > 0.f ? acc[i][0] : NEG_SLOPE * acc[i][0];
        o.y = acc[i][1] > 0.f ? acc[i][1] : NEG_SLOPE * acc[i][1];
        o.z = acc[i][2] > 0.f ? acc[i][2] : NEG_SLOPE * acc[i][2];
        o.w = acc[i][3] > 0.f ? acc[i][3] : NEG_SLOPE * acc[i][3];
        *(float4*)&out[(size_t)r * DIM + ci] = o;
        ushort4 ow;
        ow.x = f2bf(o.x * dd); ow.y = f2bf(o.y * dd);
        ow.z = f2bf(o.z * dd); ow.w = f2bf(o.w * dd);
        *(ushort4*)&outw[(size_t)r * DIM + ci] = ow;
    }
}

// ---------------- final: out = xn + x1 + lrelu(agg@W2^T+b2) + (agg@W3^T+b3) ----------------
__global__ __launch_bounds__(256) void k_final_rt(
    const float* __restrict__ agg, const float* __restrict__ xn,
    const float* __restrict__ x1,
    const float* __restrict__ W2, const float* __restrict__ b2,
    const float* __restrict__ W3, const float* __restrict__ b3,
    float* __restrict__ out, int n)
{
    __shared__ float sIn[64][65];
    __shared__ float sW2[64][65];
    __shared__ float sW3[64][65];
    int tid = threadIdx.x;
    int r0  = blockIdx.x * 64;
    #pragma unroll
    for (int i = 0; i < 16; i++) {
        int idx = tid + i * 256;
        sW2[idx >> 6][idx & 63] = W2[idx];
        sW3[idx >> 6][idx & 63] = W3[idx];
    }
    int lim = (n - r0 < 64 ? n - r0 : 64) * DIM;
    for (int idx = tid; idx < lim; idx += 256)
        sIn[idx >> 6][idx & 63] = agg[(size_t)r0 * DIM + idx];
    __syncthreads();

    int ri = (tid >> 4) << 2;
    int ci = (tid & 15) << 2;
    float acc2[4][4], acc3[4][4];
    #pragma unroll
    for (int j = 0; j < 4; j++) {
        float bj2 = b2[ci + j], bj3 = b3[ci + j];
        #pragma unroll
        for (int i = 0; i < 4; i++) { acc2[i][j] = bj2; acc3[i][j] = bj3; }
    }
    #pragma unroll 2
    for (int k = 0; k < 64; k++) {
        float a0 = sIn[ri + 0][k], a1 = sIn[ri + 1][k];
        float a2 = sIn[ri + 2][k], a3 = sIn[ri + 3][k];
        float u0 = sW2[ci + 0][k], u1 = sW2[ci + 1][k];
        float u2 = sW2[ci + 2][k], u3 = sW2[ci + 3][k];
        float v0 = sW3[ci + 0][k], v1 = sW3[ci + 1][k];
        float v2 = sW3[ci + 2][k], v3 = sW3[ci + 3][k];
        acc2[0][0] = fmaf(a0, u0, acc2[0][0]); acc2[0][1] = fmaf(a0, u1, acc2[0][1]);
        acc2[0][2] = fmaf(a0, u2, acc2[0][2]); acc2[0][3] = fmaf(a0, u3, acc2[0][3]);
        acc2[1][0] = fmaf(a1, u0, acc2[1][0]); acc2[1][1] = fmaf(a1, u1, acc2[1][1]);
        acc2[1][2] = fmaf(a1, u2, acc2[1][2]); acc2[1][3] = fmaf(a1, u3, acc2[1][3]);
        acc2[2][0] = fmaf(a2, u0, acc2[2][0]); acc2[2][1] = fmaf(a2, u1, acc2[2][1]);
        acc2[2][2] = fmaf(a2, u2, acc2[2][2]); acc2[2][3] = fmaf(a2, u3, acc2[2][3]);
        acc2[3][0] = fmaf(a3, u0, acc2[3][0]); acc2[3][1] = fmaf(a3, u1, acc2[3][1]);
        acc2[3][2] = fmaf(a3, u2, acc2[3][2]); acc2[3][3] = fmaf(a3, u3, acc2[3][3]);
        acc3[0][0] = fmaf(a0, v0, acc3[0][0]); acc3[0][1] = fmaf(a0, v1, acc3[0][1]);
        acc3[0][2] = fmaf(a0, v2, acc3[0][2]); acc3[0][3] = fmaf(a0, v3, acc3[0][3]);
        acc3[1][0] = fmaf(a1, v0, acc3[1][0]); acc3[1][1] = fmaf(a1, v1, acc3[1][1]);
        acc3[1][2] = fmaf(a1, v2, acc3[1][2]); acc3[1][3] = fmaf(a1, v3, acc3[1][3]);
        acc3[2][0] = fmaf(a2, v0, acc3[2][0]); acc3[2][1] = fmaf(a2, v1, acc3[2][1]);
        acc3[2][2] = fmaf(a2, v2, acc3[2][2]); acc3[2][3] = fmaf(a2, v3, acc3[2][3]);
        acc3[3][0] = fmaf(a3, v0, acc3[3][0]); acc3[3][1] = fmaf(a3, v1, acc3[3][1]);
        acc3[3][2] = fmaf(a3, v2, acc3[3][2]); acc3[3][3] = fmaf(a3, v3, acc3[3][3]);
    }
    #pragma unroll
    for (int i = 0; i < 4; i++) {
        int r = r0 + ri + i;
        if (r >= n) break;
        size_t base = (size_t)r * DIM + ci;
        float4 vxn = *(const float4*)&xn[base];
        float4 vx1 = *(const float4*)&x1[base];
        float4 o;
        float e0 = acc2[i][0] > 0.f ? acc2[i][0] : NEG_SLOPE * acc2[i][0];
        float e1 = acc2[i][1] > 0.f ? acc2[i][1] : NEG_SLOPE * acc2[i][1];
        float e2 = acc2[i][2] > 0.f ? acc2[i][2] : NEG_SLOPE * acc2[i][2];
        float e3 = acc2[i][3] > 0.f ? acc2[i][3] : NEG_SLOPE * acc2[i][3];
        o.x = vxn.x + vx1.x + e0 + acc3[i][0];
        o.y = vxn.y + vx1.y + e1 + acc3[i][1];
        o.z = vxn.z + vx1.z + e2 + acc3[i][2];
        o.w = vxn.w + vx1.w + e3 + acc3[i][3];
        *(float4*)&out[base] = o;
    }
}

// ---------------- launcher ----------------

extern "C" void kernel_launch(void* const* d_in, const int* in_sizes, int n_in,
                              void* d_out, int out_size, void* d_ws, size_t ws_size,
                              hipStream_t stream) {
    const int*   ei  = (const int*)d_in[0];
    const float* emb = (const float*)d_in[1];
    const float* W1  = (const float*)d_in[2];
    const float* b1  = (const float*)d_in[3];
    const float* W2  = (const float*)d_in[4];
    const float* b2  = (const float*)d_in[5];
    const float* W3  = (const float*)d_in[6];
    const float* b3  = (const float*)d_in[7];
    float* out = (float*)d_out;

    int E = in_sizes[0] / 2;
    int n = in_sizes[1] / DIM;
    size_t nD = (size_t)n * DIM;

    // bucket shift: <=256 buckets, span<=2048 (n<=524288)
    int shift = 9;
    while ((((size_t)n + ((size_t)1 << shift) - 1) >> shift) > 256) shift++;
    int nbuckets = (int)(((size_t)n + ((size_t)1 << shift) - 1) >> shift);

    // workspace layout (all regions fully initialized each call)
    size_t np = ((size_t)n + 1023) & ~1023ull;
    int*   bcnt    = (int*)d_ws;              // 256*16 (stride-16 padded)
    int*   bcur    = bcnt + 4096;             // 256*16
    int*   boffs   = bcur + 4096;             // nbuckets+1 (<=257), pad to 512
    int*   offsets = boffs + 512;             // np (n+1 used)
    float* dinv    = (float*)(offsets + np);  // np
    float* xn      = dinv + np;               // nD f32
    float* x1      = xn + nD;                 // nD f32
    float* agg     = x1 + nD;                 // nD f32 (stage aliases this)
    int*   adj     = (int*)(agg + nD);        // 2E ints
    bfraw* xnw     = (bfraw*)(adj + 2 * (size_t)E);  // nD bf16
    bfraw* x1w     = xnw + nD;                // nD bf16
    int2*  stage   = (int2*)agg;              // 2E int2 (16MB <= nD*4), dead before gather

    const int B = 256;

    // --- CSR build (no global degree atomics) ---
    k_zero_i32<<<16, B, 0, stream>>>(bcnt, 4096);
    k_bhist   <<<(E + EPH - 1) / EPH, B, 0, stream>>>(ei, E, bcnt, shift);
    k_bscan   <<<1, B, 0, stream>>>(bcnt, nbuckets, boffs, bcur, offsets, n, 2 * E);
    k_bin     <<<(E + EPW - 1) / EPW, B, 0, stream>>>(ei, E, stage, bcur, shift);
    k_bucket  <<<nbuckets, B, 0, stream>>>(stage, boffs, offsets, adj, dinv, n, shift);

    // --- xn = row-L2-normalized embedding (+ prescaled bf16) ---
    k_normalize<<<(n + 3) / 4, B, 0, stream>>>(emb, dinv, xn, xnw, n);

    // --- layer 1 ---
    k_gather   <<<(n + 3) / 4, B, 0, stream>>>(adj, offsets, dinv, xnw, xn, agg, n);
    k_linear_rt<<<(n + 63) / 64, B, 0, stream>>>(agg, W1, b1, dinv, x1, x1w, n);

    // --- layers 2+3 fused ---
    k_gather   <<<(n + 3) / 4, B, 0, stream>>>(adj, offsets, dinv, x1w, x1, agg, n);
    k_final_rt <<<(n + 63) / 64, B, 0, stream>>>(agg, xn, x1, W2, b2, W3, b3, out, n);
}

// Round 7
// 252.335 us; speedup vs baseline: 4.5741x; 1.1557x over previous
//
#include <hip/hip_runtime.h>
#include <math.h>

#define DIM 64
#define NEG_SLOPE 0.01f

typedef unsigned short bfraw;

__device__ __forceinline__ bfraw f2bf(float f) {
    unsigned int u = __float_as_uint(f);
    unsigned int r = (u + 0x7FFFu + ((u >> 16) & 1u)) >> 16;  // RNE
    return (bfraw)r;
}
__device__ __forceinline__ float bf2f(bfraw h) {
    return __uint_as_float(((unsigned int)h) << 16);
}

// ---------------- small utility ----------------

__global__ void k_zero_i32(int* __restrict__ p, int n) {
    int i = blockIdx.x * blockDim.x + threadIdx.x;
    if (i < n) p[i] = 0;
}

// ---------------- bucket histogram (LDS-aggregated; bcnt stride-16 padded) ----------------
#define EPH 8192

__global__ __launch_bounds__(256) void k_bhist(const int* __restrict__ ei, int E,
                                               int* __restrict__ bcnt, int shift) {
    __shared__ int hist[256];
    int t = threadIdx.x;
    hist[t] = 0;
    __syncthreads();
    int e0 = blockIdx.x * EPH;
    int e1 = e0 + EPH < E ? e0 + EPH : E;
    for (int e = e0 + t; e < e1; e += 256) {
        int u = ei[e], v = ei[E + e];
        atomicAdd(&hist[u >> shift], 1);
        atomicAdd(&hist[v >> shift], 1);
    }
    __syncthreads();
    if (hist[t]) atomicAdd(&bcnt[t * 16], hist[t]);
}

// single WG: exclusive-scan bucket counts -> boffs[nbuckets+1], init bcur, offsets[n]
__global__ __launch_bounds__(256) void k_bscan(const int* __restrict__ bcnt, int nbuckets,
                                               int* __restrict__ boffs, int* __restrict__ bcur,
                                               int* __restrict__ offsets, int n, int E2) {
    __shared__ int ls[256];
    int t = threadIdx.x;
    int own = (t < nbuckets) ? bcnt[t * 16] : 0;
    ls[t] = own;
    __syncthreads();
    for (int off = 1; off < 256; off <<= 1) {
        int v = (t >= off) ? ls[t - off] : 0;
        __syncthreads();
        ls[t] += v;
        __syncthreads();
    }
    int excl = ls[t] - own;
    if (t < nbuckets) { boffs[t] = excl; bcur[t * 16] = excl; }
    if (t == 0) { boffs[nbuckets] = E2; offsets[n] = E2; }
}

// ---------------- bin records (dst,src) into bucket-contiguous stage ----------------
#define EPW 2048

__global__ __launch_bounds__(256) void k_bin(const int* __restrict__ ei, int E,
                                             int2* __restrict__ stage,
                                             int* __restrict__ bcur, int shift) {
    __shared__ int hist[256];
    __shared__ int cur[256];
    int t = threadIdx.x;
    hist[t] = 0;
    __syncthreads();
    int e0 = blockIdx.x * EPW;
    int e1 = e0 + EPW < E ? e0 + EPW : E;
    for (int e = e0 + t; e < e1; e += 256) {
        int u = ei[e], v = ei[E + e];
        atomicAdd(&hist[u >> shift], 1);
        atomicAdd(&hist[v >> shift], 1);
    }
    __syncthreads();
    cur[t] = hist[t] > 0 ? atomicAdd(&bcur[t * 16], hist[t]) : 0;
    __syncthreads();
    for (int e = e0 + t; e < e1; e += 256) {
        int u = ei[e], v = ei[E + e];
        int s1 = atomicAdd(&cur[v >> shift], 1);
        stage[s1] = make_int2(v, u);
        int s2 = atomicAdd(&cur[u >> shift], 1);
        stage[s2] = make_int2(u, v);
    }
}

// ---------------- per-bucket: degree count + local scan -> offsets/dinv, then place ----------------
__global__ __launch_bounds__(256) void k_bucket(const int2* __restrict__ stage,
                                                const int* __restrict__ boffs,
                                                int* __restrict__ offsets,
                                                int* __restrict__ adj,
                                                float* __restrict__ dinv,
                                                int n, int shift) {
    __shared__ int deg[2048];   // per-node degree, then reused as placement cursor
    __shared__ int scan[256];
    int t = threadIdx.x;
    int span  = 1 << shift;
    int node0 = blockIdx.x << shift;
    int cnt = n - node0 < span ? n - node0 : span;
    for (int i = t; i < cnt; i += 256) deg[i] = 0;
    __syncthreads();
    int jbeg = boffs[blockIdx.x], jend = boffs[blockIdx.x + 1];
    for (int j = jbeg + t; j < jend; j += 256)
        atomicAdd(&deg[stage[j].x - node0], 1);
    __syncthreads();
    int per  = span >> 8;
    int base = t * per;
    int s = 0;
    for (int k = 0; k < per; k++) { int i = base + k; if (i < cnt) s += deg[i]; }
    scan[t] = s;
    __syncthreads();
    for (int off = 1; off < 256; off <<= 1) {
        int v = (t >= off) ? scan[t - off] : 0;
        __syncthreads();
        scan[t] += v;
        __syncthreads();
    }
    int run = jbeg + scan[t] - s;
    for (int k = 0; k < per; k++) {
        int i = base + k;
        if (i < cnt) {
            int d = deg[i];
            offsets[node0 + i] = run;
            dinv[node0 + i] = rsqrtf(1.0f + (float)d);
            deg[i] = run;
            run += d;
        }
    }
    __syncthreads();
    for (int j = jbeg + t; j < jend; j += 256) {
        int2 r = stage[j];
        int slot = atomicAdd(&deg[r.x - node0], 1);
        adj[slot] = r.y;
    }
}

// ---------------- row L2-normalize + prescaled bf16 copy ----------------
__global__ void k_normalize(const float* __restrict__ x, const float* __restrict__ dinv,
                            float* __restrict__ xn, bfraw* __restrict__ xnw, int n) {
    int row  = (blockIdx.x * blockDim.x + threadIdx.x) >> 6;
    int lane = threadIdx.x & 63;
    if (row >= n) return;
    float v = x[row * DIM + lane];
    float s = v * v;
    #pragma unroll
    for (int off = 32; off; off >>= 1) s += __shfl_xor(s, off);
    float scale = 1.0f / fmaxf(sqrtf(s), 1e-12f);
    float xv = v * scale;
    xn[row * DIM + lane] = xv;
    xnw[row * DIM + lane] = f2bf(xv * dinv[row]);
}

// ---------------- CSR gather (bf16 prescaled rows, 2 rows in flight per load) ----------------
// dst[d] = dinv[d] * ( sum_j srcw[adj_j]  +  dinv[d]*src[d] ),  srcw = bf16(dinv*src)
// Half-wave (32 lanes) reads one row as uint (2 bf16/lane); half 0 takes even
// neighbor slots, half 1 odd; __shfl_xor(32) combines at the end.
__global__ void k_gather(const int* __restrict__ adj, const int* __restrict__ offsets,
                         const float* __restrict__ dinv,
                         const bfraw* __restrict__ srcw, const float* __restrict__ src,
                         float* __restrict__ dst, int n) {
    int w    = (blockIdx.x * blockDim.x + threadIdx.x) >> 6;  // wave per node
    int lane = threadIdx.x & 63;
    if (w >= n) return;
    int half = lane >> 5;
    int hl   = lane & 31;
    int beg = offsets[w], end = offsets[w + 1];
    float dd = dinv[w];
    const unsigned int* s2 = (const unsigned int*)srcw;  // 1 uint = elems {2hl, 2hl+1}
    float ax = 0.f, ay = 0.f;
    int j = beg;
    for (; j + 16 <= end; j += 16) {               // 8 loads -> 16 rows in flight
        #pragma unroll
        for (int k = 0; k < 8; k++) {
            int sidx = adj[j + 2 * k + half];
            unsigned int pv = s2[(size_t)sidx * 32 + hl];
            ax += bf2f((bfraw)(pv & 0xFFFFu));
            ay += bf2f((bfraw)(pv >> 16));
        }
    }
    if (j + 8 <= end) {                            // 4 loads -> 8 rows
        #pragma unroll
        for (int k = 0; k < 4; k++) {
            int sidx = adj[j + 2 * k + half];
            unsigned int pv = s2[(size_t)sidx * 32 + hl];
            ax += bf2f((bfraw)(pv & 0xFFFFu));
            ay += bf2f((bfraw)(pv >> 16));
        }
        j += 8;
    }
    if (j + 4 <= end) {                            // 2 loads -> 4 rows
        #pragma unroll
        for (int k = 0; k < 2; k++) {
            int sidx = adj[j + 2 * k + half];
            unsigned int pv = s2[(size_t)sidx * 32 + hl];
            ax += bf2f((bfraw)(pv & 0xFFFFu));
            ay += bf2f((bfraw)(pv >> 16));
        }
        j += 4;
    }
    if (j + 2 <= end) {                            // 1 load -> 2 rows
        int sidx = adj[j + half];
        unsigned int pv = s2[(size_t)sidx * 32 + hl];
        ax += bf2f((bfraw)(pv & 0xFFFFu));
        ay += bf2f((bfraw)(pv >> 16));
        j += 2;
    }
    if (j < end) {                                 // last row: half 0 only
        int sidx = adj[j];
        unsigned int pv = (half == 0) ? s2[(size_t)sidx * 32 + hl] : 0u;
        ax += bf2f((bfraw)(pv & 0xFFFFu));
        ay += bf2f((bfraw)(pv >> 16));
    }
    ax += __shfl_xor(ax, 32);
    ay += __shfl_xor(ay, 32);
    if (half == 0) {
        float2 sv = ((const float2*)(src + (size_t)w * DIM))[hl];
        float2 o;
        o.x = dd * (ax + dd * sv.x);
        o.y = dd * (ay + dd * sv.y);
        ((float2*)(dst + (size_t)w * DIM))[hl] = o;
    }
}

// ---------------- register-tiled linear: x1 = lrelu(in @ W^T + b), + bf16 prescaled copy ----------------
__global__ __launch_bounds__(256) void k_linear_rt(
    const float* __restrict__ in, const float* __restrict__ W,
    const float* __restrict__ b, const float* __restrict__ dinv,
    float* __restrict__ out, bfraw* __restrict__ outw, int n)
{
    __shared__ float sIn[64][65];
    __shared__ float sW[64][65];
    int tid = threadIdx.x;
    int r0  = blockIdx.x * 64;
    #pragma unroll
    for (int i = 0; i < 16; i++) {
        int idx = tid + i * 256;
        sW[idx >> 6][idx & 63] = W[idx];
    }
    int lim = (n - r0 < 64 ? n - r0 : 64) * DIM;
    for (int idx = tid; idx < lim; idx += 256)
        sIn[idx >> 6][idx & 63] = in[(size_t)r0 * DIM + idx];
    __syncthreads();

    int ri = (tid >> 4) << 2;
    int ci = (tid & 15) << 2;
    float acc[4][4];
    #pragma unroll
    for (int j = 0; j < 4; j++) {
        float bj = b[ci + j];
        #pragma unroll
        for (int i = 0; i < 4; i++) acc[i][j] = bj;
    }
    #pragma unroll 4
    for (int k = 0; k < 64; k++) {
        float a0 = sIn[ri + 0][k], a1 = sIn[ri + 1][k];
        float a2 = sIn[ri + 2][k], a3 = sIn[ri + 3][k];
        float w0 = sW[ci + 0][k], w1 = sW[ci + 1][k];
        float w2 = sW[ci + 2][k], w3 = sW[ci + 3][k];
        acc[0][0] = fmaf(a0, w0, acc[0][0]); acc[0][1] = fmaf(a0, w1, acc[0][1]);
        acc[0][2] = fmaf(a0, w2, acc[0][2]); acc[0][3] = fmaf(a0, w3, acc[0][3]);
        acc[1][0] = fmaf(a1, w0, acc[1][0]); acc[1][1] = fmaf(a1, w1, acc[1][1]);
        acc[1][2] = fmaf(a1, w2, acc[1][2]); acc[1][3] = fmaf(a1, w3, acc[1][3]);
        acc[2][0] = fmaf(a2, w0, acc[2][0]); acc[2][1] = fmaf(a2, w1, acc[2][1]);
        acc[2][2] = fmaf(a2, w2, acc[2][2]); acc[2][3] = fmaf(a2, w3, acc[2][3]);
        acc[3][0] = fmaf(a3, w0, acc[3][0]); acc[3][1] = fmaf(a3, w1, acc[3][1]);
        acc[3][2] = fmaf(a3, w2, acc[3][2]); acc[3][3] = fmaf(a3, w3, acc[3][3]);
    }
    #pragma unroll
    for (int i = 0; i < 4; i++) {
        int r = r0 + ri + i;
        if (r >= n) break;
        float dd = dinv[r];
        float4 o;
        o.x = acc[i][0] > 0.f ? acc[i][0] : NEG_SLOPE * acc[i][0];
        o.y = acc[i][1] > 0.f ? acc[i][1] : NEG_SLOPE * acc[i][1];
        o.z = acc[i][2] > 0.f ? acc[i][2] : NEG_SLOPE * acc[i][2];
        o.w = acc[i][3] > 0.f ? acc[i][3] : NEG_SLOPE * acc[i][3];
        *(float4*)&out[(size_t)r * DIM + ci] = o;
        ushort4 ow;
        ow.x = f2bf(o.x * dd); ow.y = f2bf(o.y * dd);
        ow.z = f2bf(o.z * dd); ow.w = f2bf(o.w * dd);
        *(ushort4*)&outw[(size_t)r * DIM + ci] = ow;
    }
}

// ---------------- final: out = xn + x1 + lrelu(agg@W2^T+b2) + (agg@W3^T+b3) ----------------
__global__ __launch_bounds__(256) void k_final_rt(
    const float* __restrict__ agg, const float* __restrict__ xn,
    const float* __restrict__ x1,
    const float* __restrict__ W2, const float* __restrict__ b2,
    const float* __restrict__ W3, const float* __restrict__ b3,
    float* __restrict__ out, int n)
{
    __shared__ float sIn[64][65];
    __shared__ float sW2[64][65];
    __shared__ float sW3[64][65];
    int tid = threadIdx.x;
    int r0  = blockIdx.x * 64;
    #pragma unroll
    for (int i = 0; i < 16; i++) {
        int idx = tid + i * 256;
        sW2[idx >> 6][idx & 63] = W2[idx];
        sW3[idx >> 6][idx & 63] = W3[idx];
    }
    int lim = (n - r0 < 64 ? n - r0 : 64) * DIM;
    for (int idx = tid; idx < lim; idx += 256)
        sIn[idx >> 6][idx & 63] = agg[(size_t)r0 * DIM + idx];
    __syncthreads();

    int ri = (tid >> 4) << 2;
    int ci = (tid & 15) << 2;
    float acc2[4][4], acc3[4][4];
    #pragma unroll
    for (int j = 0; j < 4; j++) {
        float bj2 = b2[ci + j], bj3 = b3[ci + j];
        #pragma unroll
        for (int i = 0; i < 4; i++) { acc2[i][j] = bj2; acc3[i][j] = bj3; }
    }
    #pragma unroll 2
    for (int k = 0; k < 64; k++) {
        float a0 = sIn[ri + 0][k], a1 = sIn[ri + 1][k];
        float a2 = sIn[ri + 2][k], a3 = sIn[ri + 3][k];
        float u0 = sW2[ci + 0][k], u1 = sW2[ci + 1][k];
        float u2 = sW2[ci + 2][k], u3 = sW2[ci + 3][k];
        float v0 = sW3[ci + 0][k], v1 = sW3[ci + 1][k];
        float v2 = sW3[ci + 2][k], v3 = sW3[ci + 3][k];
        acc2[0][0] = fmaf(a0, u0, acc2[0][0]); acc2[0][1] = fmaf(a0, u1, acc2[0][1]);
        acc2[0][2] = fmaf(a0, u2, acc2[0][2]); acc2[0][3] = fmaf(a0, u3, acc2[0][3]);
        acc2[1][0] = fmaf(a1, u0, acc2[1][0]); acc2[1][1] = fmaf(a1, u1, acc2[1][1]);
        acc2[1][2] = fmaf(a1, u2, acc2[1][2]); acc2[1][3] = fmaf(a1, u3, acc2[1][3]);
        acc2[2][0] = fmaf(a2, u0, acc2[2][0]); acc2[2][1] = fmaf(a2, u1, acc2[2][1]);
        acc2[2][2] = fmaf(a2, u2, acc2[2][2]); acc2[2][3] = fmaf(a2, u3, acc2[2][3]);
        acc2[3][0] = fmaf(a3, u0, acc2[3][0]); acc2[3][1] = fmaf(a3, u1, acc2[3][1]);
        acc2[3][2] = fmaf(a3, u2, acc2[3][2]); acc2[3][3] = fmaf(a3, u3, acc2[3][3]);
        acc3[0][0] = fmaf(a0, v0, acc3[0][0]); acc3[0][1] = fmaf(a0, v1, acc3[0][1]);
        acc3[0][2] = fmaf(a0, v2, acc3[0][2]); acc3[0][3] = fmaf(a0, v3, acc3[0][3]);
        acc3[1][0] = fmaf(a1, v0, acc3[1][0]); acc3[1][1] = fmaf(a1, v1, acc3[1][1]);
        acc3[1][2] = fmaf(a1, v2, acc3[1][2]); acc3[1][3] = fmaf(a1, v3, acc3[1][3]);
        acc3[2][0] = fmaf(a2, v0, acc3[2][0]); acc3[2][1] = fmaf(a2, v1, acc3[2][1]);
        acc3[2][2] = fmaf(a2, v2, acc3[2][2]); acc3[2][3] = fmaf(a2, v3, acc3[2][3]);
        acc3[3][0] = fmaf(a3, v0, acc3[3][0]); acc3[3][1] = fmaf(a3, v1, acc3[3][1]);
        acc3[3][2] = fmaf(a3, v2, acc3[3][2]); acc3[3][3] = fmaf(a3, v3, acc3[3][3]);
    }
    #pragma unroll
    for (int i = 0; i < 4; i++) {
        int r = r0 + ri + i;
        if (r >= n) break;
        size_t base = (size_t)r * DIM + ci;
        float4 vxn = *(const float4*)&xn[base];
        float4 vx1 = *(const float4*)&x1[base];
        float4 o;
        float e0 = acc2[i][0] > 0.f ? acc2[i][0] : NEG_SLOPE * acc2[i][0];
        float e1 = acc2[i][1] > 0.f ? acc2[i][1] : NEG_SLOPE * acc2[i][1];
        float e2 = acc2[i][2] > 0.f ? acc2[i][2] : NEG_SLOPE * acc2[i][2];
        float e3 = acc2[i][3] > 0.f ? acc2[i][3] : NEG_SLOPE * acc2[i][3];
        o.x = vxn.x + vx1.x + e0 + acc3[i][0];
        o.y = vxn.y + vx1.y + e1 + acc3[i][1];
        o.z = vxn.z + vx1.z + e2 + acc3[i][2];
        o.w = vxn.w + vx1.w + e3 + acc3[i][3];
        *(float4*)&out[base] = o;
    }
}

// ---------------- launcher ----------------

extern "C" void kernel_launch(void* const* d_in, const int* in_sizes, int n_in,
                              void* d_out, int out_size, void* d_ws, size_t ws_size,
                              hipStream_t stream) {
    const int*   ei  = (const int*)d_in[0];
    const float* emb = (const float*)d_in[1];
    const float* W1  = (const float*)d_in[2];
    const float* b1  = (const float*)d_in[3];
    const float* W2  = (const float*)d_in[4];
    const float* b2  = (const float*)d_in[5];
    const float* W3  = (const float*)d_in[6];
    const float* b3  = (const float*)d_in[7];
    float* out = (float*)d_out;

    int E = in_sizes[0] / 2;
    int n = in_sizes[1] / DIM;
    size_t nD = (size_t)n * DIM;

    // bucket shift: <=256 buckets, span<=2048 (n<=524288)
    int shift = 9;
    while ((((size_t)n + ((size_t)1 << shift) - 1) >> shift) > 256) shift++;
    int nbuckets = (int)(((size_t)n + ((size_t)1 << shift) - 1) >> shift);

    // workspace layout (all regions fully initialized each call)
    size_t np = ((size_t)n + 1023) & ~1023ull;
    int*   bcnt    = (int*)d_ws;              // 256*16 (stride-16 padded)
    int*   bcur    = bcnt + 4096;             // 256*16
    int*   boffs   = bcur + 4096;             // nbuckets+1 (<=257), pad to 512
    int*   offsets = boffs + 512;             // np (n+1 used)
    float* dinv    = (float*)(offsets + np);  // np
    float* xn      = dinv + np;               // nD f32
    float* x1      = xn + nD;                 // nD f32
    float* agg     = x1 + nD;                 // nD f32 (stage aliases this)
    int*   adj     = (int*)(agg + nD);        // 2E ints
    bfraw* xnw     = (bfraw*)(adj + 2 * (size_t)E);  // nD bf16
    bfraw* x1w     = xnw + nD;                // nD bf16
    int2*  stage   = (int2*)agg;              // 2E int2 (16MB <= nD*4), dead before gather

    const int B = 256;

    // --- CSR build (no global degree atomics) ---
    k_zero_i32<<<16, B, 0, stream>>>(bcnt, 4096);
    k_bhist   <<<(E + EPH - 1) / EPH, B, 0, stream>>>(ei, E, bcnt, shift);
    k_bscan   <<<1, B, 0, stream>>>(bcnt, nbuckets, boffs, bcur, offsets, n, 2 * E);
    k_bin     <<<(E + EPW - 1) / EPW, B, 0, stream>>>(ei, E, stage, bcur, shift);
    k_bucket  <<<nbuckets, B, 0, stream>>>(stage, boffs, offsets, adj, dinv, n, shift);

    // --- xn = row-L2-normalized embedding (+ prescaled bf16) ---
    k_normalize<<<(n + 3) / 4, B, 0, stream>>>(emb, dinv, xn, xnw, n);

    // --- layer 1 ---
    k_gather   <<<(n + 3) / 4, B, 0, stream>>>(adj, offsets, dinv, xnw, xn, agg, n);
    k_linear_rt<<<(n + 63) / 64, B, 0, stream>>>(agg, W1, b1, dinv, x1, x1w, n);

    // --- layers 2+3 fused ---
    k_gather   <<<(n + 3) / 4, B, 0, stream>>>(adj, offsets, dinv, x1w, x1, agg, n);
    k_final_rt <<<(n + 63) / 64, B, 0, stream>>>(agg, xn, x1, W2, b2, W3, b3, out, n);
}